// Round 4
// baseline (1531.185 us; speedup 1.0000x reference)
//
#include <hip/hip_runtime.h>

#define EMB 64
#define BROWS 512            // rows per bucket
#define BSHIFT 9             // log2(BROWS)
#define CHUNK 4096           // edges per partition block
#define COLBITS 23
#define COLMASK ((1u << COLBITS) - 1u)

// bf16 helpers (manual RNE pack/unpack)
__device__ __forceinline__ unsigned short f2bf(float f) {
    unsigned u = __float_as_uint(f);
    u = u + 0x7FFFu + ((u >> 16) & 1u);
    return (unsigned short)(u >> 16);
}
__device__ __forceinline__ float bf2f(unsigned short s) {
    return __uint_as_float(((unsigned)s) << 16);
}

// K0: convert left (f32) -> left16 (bf16), 2 elems/thread
__global__ void convert_left_kernel(const float* __restrict__ left,
                                    unsigned* __restrict__ left16, int n2) {
    int i = blockIdx.x * blockDim.x + threadIdx.x;
    if (i >= n2) return;
    float2 v = ((const float2*)left)[i];
    left16[i] = (unsigned)f2bf(v.x) | ((unsigned)f2bf(v.y) << 16);
}

// K1: bucket histogram (into bbase[0..nb)) + total = sum(w)
__global__ __launch_bounds__(256) void hist_total_kernel(
    const int2* __restrict__ eidx, const float* __restrict__ w, int n_edges,
    int nb, int* __restrict__ bcount, float* __restrict__ total) {
    __shared__ int lh[256];
    int t = threadIdx.x;
    lh[t] = 0;
    __syncthreads();
    int gid = blockIdx.x * 256 + t;
    int stride = gridDim.x * 256;
    float s = 0.f;
    for (int e = gid; e < n_edges; e += stride) {
        s += w[e];
        atomicAdd(&lh[eidx[e].x >> BSHIFT], 1);
    }
    #pragma unroll
    for (int off = 32; off > 0; off >>= 1) s += __shfl_down(s, off, 64);
    if ((t & 63) == 0) atomicAdd(total, s);
    __syncthreads();
    if (t < nb && lh[t]) atomicAdd(&bcount[t], lh[t]);
}

// K2: single-block exclusive scan of bucket counts (nb <= 256), in place.
// bbase[b] = exclusive offset; bcursor[b] = copy; bbase[nb] = n_edges
__global__ __launch_bounds__(256) void bucket_scan_kernel(
    int* __restrict__ bbase, int* __restrict__ bcursor, int nb, int n_edges) {
    __shared__ int ssc[256];
    int t = threadIdx.x;
    int v = (t < nb) ? bbase[t] : 0;
    ssc[t] = v;
    __syncthreads();
    for (int off = 1; off < 256; off <<= 1) {
        int u = (t >= off) ? ssc[t - off] : 0;
        __syncthreads();
        ssc[t] += u;
        __syncthreads();
    }
    int excl = ssc[t] - v;
    if (t < nb) { bbase[t] = excl; bcursor[t] = excl; }
    if (t == 0) bbase[nb] = n_edges;
}

// K3: partition edges into buckets with LDS staging for coalesced writes.
// sorted[i] = ( (row_local << COLBITS) | col , bits(w) ), bucket-contiguous.
__global__ __launch_bounds__(256) void partition_kernel(
    const int2* __restrict__ eidx, const float* __restrict__ w, int n_edges,
    int nb, int* __restrict__ bcursor, int2* __restrict__ sorted) {
    __shared__ int lh[256];
    __shared__ int lo[256];
    __shared__ int go[256];
    __shared__ int lcur[256];
    __shared__ int2 stage[CHUNK];
    __shared__ int dstg[CHUNK];
    int t = threadIdx.x;
    int base = blockIdx.x * CHUNK;
    int cnt = min(CHUNK, n_edges - base);

    lh[t] = 0;
    __syncthreads();
    #pragma unroll
    for (int k = 0; k < CHUNK / 256; ++k) {
        int e = base + t + k * 256;
        if (e < n_edges) atomicAdd(&lh[eidx[e].x >> BSHIFT], 1);
    }
    __syncthreads();
    int v = lh[t];
    // block scan (Hillis-Steele) of lh -> exclusive
    lo[t] = v;
    __syncthreads();
    for (int off = 1; off < 256; off <<= 1) {
        int u = (t >= off) ? lo[t - off] : 0;
        __syncthreads();
        lo[t] += u;
        __syncthreads();
    }
    int excl = lo[t] - v;
    // reserve global space for this block's share of bucket t
    go[t] = (v > 0) ? atomicAdd(&bcursor[t], v) : 0;
    __syncthreads();
    lo[t] = excl;
    lcur[t] = excl;
    __syncthreads();

    #pragma unroll
    for (int k = 0; k < CHUNK / 256; ++k) {
        int e = base + t + k * 256;
        if (e < n_edges) {
            int2 rc = eidx[e];
            float wv = w[e];
            int b = rc.x >> BSHIFT;
            unsigned rl = (unsigned)(rc.x & (BROWS - 1));
            int p = atomicAdd(&lcur[b], 1);
            stage[p] = make_int2((int)((rl << COLBITS) | (unsigned)rc.y),
                                 __float_as_int(wv));
            dstg[p] = go[b] + (p - lo[b]);
        }
    }
    __syncthreads();
    #pragma unroll
    for (int k = 0; k < CHUNK / 256; ++k) {
        int s = t + k * 256;
        if (s < cnt) sorted[dstg[s]] = stage[s];
    }
}

// K4: one block per bucket. LDS f32 accumulator (BROWS x EMB = 128 KB dynamic).
// conv accumulate via ds_add, then h = right + t1*(c - conv/total) written out.
__global__ __launch_bounds__(1024) void bucket_accum_kernel(
    const int2* __restrict__ sorted, const int* __restrict__ bbase,
    const unsigned short* __restrict__ left16,
    const float* __restrict__ right, const float* __restrict__ c,
    const float* __restrict__ temp, const float* __restrict__ total,
    float* __restrict__ hout, int n_right) {
    extern __shared__ float acc[];   // BROWS*EMB floats
    int t = threadIdx.x;
    int b = blockIdx.x;
    int lane = t & 63;
    int wv = t >> 6;                 // wave id 0..15

    float4* a4 = (float4*)acc;
    #pragma unroll 2
    for (int i = t; i < BROWS * EMB / 4; i += 1024)
        a4[i] = make_float4(0.f, 0.f, 0.f, 0.f);
    __syncthreads();

    int start = bbase[b];
    int end = bbase[b + 1];
    int m = end - start;
    int G = (m + 3) >> 2;            // groups of 4 edges
    for (int g = wv; g < G; g += 16) {
        int e0 = start + (g << 2);
        if (e0 + 4 <= end) {
            int2 sa = sorted[e0 + 0];
            int2 sb = sorted[e0 + 1];
            int2 sc = sorted[e0 + 2];
            int2 sd = sorted[e0 + 3];
            unsigned pa = (unsigned)sa.x, pb = (unsigned)sb.x;
            unsigned pc = (unsigned)sc.x, pd = (unsigned)sd.x;
            float va = bf2f(left16[(size_t)(pa & COLMASK) * EMB + lane]);
            float vb = bf2f(left16[(size_t)(pb & COLMASK) * EMB + lane]);
            float vc = bf2f(left16[(size_t)(pc & COLMASK) * EMB + lane]);
            float vd = bf2f(left16[(size_t)(pd & COLMASK) * EMB + lane]);
            atomicAdd(&acc[(pa >> COLBITS) * EMB + lane], __int_as_float(sa.y) * va);
            atomicAdd(&acc[(pb >> COLBITS) * EMB + lane], __int_as_float(sb.y) * vb);
            atomicAdd(&acc[(pc >> COLBITS) * EMB + lane], __int_as_float(sc.y) * vc);
            atomicAdd(&acc[(pd >> COLBITS) * EMB + lane], __int_as_float(sd.y) * vd);
        } else {
            for (int e = e0; e < end; ++e) {
                int2 se = sorted[e];
                unsigned pk = (unsigned)se.x;
                float vv = bf2f(left16[(size_t)(pk & COLMASK) * EMB + lane]);
                atomicAdd(&acc[(pk >> COLBITS) * EMB + lane],
                          __int_as_float(se.y) * vv);
            }
        }
    }
    __syncthreads();

    float inv = 1.0f / fmaxf(total[0], 1.0f);
    float t1 = temp[1];
    int row0 = b * BROWS;
    for (int rl = wv; rl < BROWS; rl += 16) {
        int gr = row0 + rl;
        if (gr < n_right) {
            float conv = acc[rl * EMB + lane] * inv;
            float h = right[(size_t)gr * EMB + lane] + t1 * (c[gr] - conv);
            hout[(size_t)gr * EMB + lane] = h;
        }
    }
}

// K5: MLP on h (in place in io): out = relu(h@W1^T+b1)@W2^T+b2
__global__ __launch_bounds__(256, 1) void mlp_kernel(
    const float* __restrict__ W1, const float* __restrict__ b1,
    const float* __restrict__ W2, const float* __restrict__ b2,
    float* __restrict__ io, int n) {
    int r = blockIdx.x * blockDim.x + threadIdx.x;
    if (r >= n) return;

    float h[EMB];
    const float4* qp = (const float4*)(io + (size_t)r * EMB);
    #pragma unroll
    for (int q = 0; q < EMB / 4; ++q) {
        float4 qv = qp[q];
        h[4 * q + 0] = qv.x;
        h[4 * q + 1] = qv.y;
        h[4 * q + 2] = qv.z;
        h[4 * q + 3] = qv.w;
    }

    float h1[EMB];
    #pragma unroll
    for (int j = 0; j < EMB; j += 4) {
        float s0 = b1[j + 0], s1 = b1[j + 1], s2 = b1[j + 2], s3 = b1[j + 3];
        #pragma unroll
        for (int k = 0; k < EMB; ++k) {
            float hk = h[k];
            s0 = fmaf(hk, W1[(j + 0) * EMB + k], s0);
            s1 = fmaf(hk, W1[(j + 1) * EMB + k], s1);
            s2 = fmaf(hk, W1[(j + 2) * EMB + k], s2);
            s3 = fmaf(hk, W1[(j + 3) * EMB + k], s3);
        }
        h1[j + 0] = fmaxf(s0, 0.f);
        h1[j + 1] = fmaxf(s1, 0.f);
        h1[j + 2] = fmaxf(s2, 0.f);
        h1[j + 3] = fmaxf(s3, 0.f);
    }

    float4* op = (float4*)(io + (size_t)r * EMB);
    #pragma unroll
    for (int j = 0; j < EMB; j += 4) {
        float s0 = b2[j + 0], s1 = b2[j + 1], s2 = b2[j + 2], s3 = b2[j + 3];
        #pragma unroll
        for (int k = 0; k < EMB; ++k) {
            float hk = h1[k];
            s0 = fmaf(hk, W2[(j + 0) * EMB + k], s0);
            s1 = fmaf(hk, W2[(j + 1) * EMB + k], s1);
            s2 = fmaf(hk, W2[(j + 2) * EMB + k], s2);
            s3 = fmaf(hk, W2[(j + 3) * EMB + k], s3);
        }
        op[j / 4] = make_float4(s0, s1, s2, s3);
    }
}

// ===================== fallback (atomic path) =====================

__global__ void sum_weights_kernel(const float* __restrict__ w, int n,
                                   float* __restrict__ total) {
    int gid = blockIdx.x * blockDim.x + threadIdx.x;
    int stride = gridDim.x * blockDim.x;
    float s = 0.f;
    for (int i = gid; i < n; i += stride) s += w[i];
    #pragma unroll
    for (int off = 32; off > 0; off >>= 1) s += __shfl_down(s, off, 64);
    if ((threadIdx.x & 63) == 0) atomicAdd(total, s);
}

__global__ void edge_scatter_kernel(const int* __restrict__ idx,
                                    const float* __restrict__ w,
                                    const float* __restrict__ left,
                                    const float* __restrict__ total,
                                    float* __restrict__ conv,
                                    long long n_threads) {
    long long gid = (long long)blockIdx.x * blockDim.x + threadIdx.x;
    if (gid >= n_threads) return;
    int e = (int)(gid >> 6);
    int d = (int)(gid & 63);
    float inv = 1.0f / fmaxf(total[0], 1.0f);
    int row = idx[2 * e];
    int col = idx[2 * e + 1];
    float v = w[e] * inv;
    float msg = left[(size_t)col * EMB + d] * v;
    atomicAdd(&conv[(size_t)row * EMB + d], msg);
}

__global__ __launch_bounds__(256, 1) void fused_mlp_kernel(
    const float* __restrict__ right, const float* __restrict__ c,
    const float* __restrict__ temp,
    const float* __restrict__ W1, const float* __restrict__ b1,
    const float* __restrict__ W2, const float* __restrict__ b2,
    float* __restrict__ io, int n) {
    int r = blockIdx.x * blockDim.x + threadIdx.x;
    if (r >= n) return;
    float t1 = temp[1];
    float cv = c[r];
    float h[EMB];
    const float4* rp = (const float4*)(right + (size_t)r * EMB);
    const float4* qp = (const float4*)(io + (size_t)r * EMB);
    #pragma unroll
    for (int q = 0; q < EMB / 4; ++q) {
        float4 rv = rp[q];
        float4 qv = qp[q];
        h[4 * q + 0] = rv.x + t1 * (cv - qv.x);
        h[4 * q + 1] = rv.y + t1 * (cv - qv.y);
        h[4 * q + 2] = rv.z + t1 * (cv - qv.z);
        h[4 * q + 3] = rv.w + t1 * (cv - qv.w);
    }
    float h1[EMB];
    #pragma unroll
    for (int j = 0; j < EMB; j += 4) {
        float s0 = b1[j], s1 = b1[j + 1], s2 = b1[j + 2], s3 = b1[j + 3];
        #pragma unroll
        for (int k = 0; k < EMB; ++k) {
            float hk = h[k];
            s0 = fmaf(hk, W1[(j + 0) * EMB + k], s0);
            s1 = fmaf(hk, W1[(j + 1) * EMB + k], s1);
            s2 = fmaf(hk, W1[(j + 2) * EMB + k], s2);
            s3 = fmaf(hk, W1[(j + 3) * EMB + k], s3);
        }
        h1[j] = fmaxf(s0, 0.f);
        h1[j + 1] = fmaxf(s1, 0.f);
        h1[j + 2] = fmaxf(s2, 0.f);
        h1[j + 3] = fmaxf(s3, 0.f);
    }
    float4* op = (float4*)(io + (size_t)r * EMB);
    #pragma unroll
    for (int j = 0; j < EMB; j += 4) {
        float s0 = b2[j], s1 = b2[j + 1], s2 = b2[j + 2], s3 = b2[j + 3];
        #pragma unroll
        for (int k = 0; k < EMB; ++k) {
            float hk = h1[k];
            s0 = fmaf(hk, W2[(j + 0) * EMB + k], s0);
            s1 = fmaf(hk, W2[(j + 1) * EMB + k], s1);
            s2 = fmaf(hk, W2[(j + 2) * EMB + k], s2);
            s3 = fmaf(hk, W2[(j + 3) * EMB + k], s3);
        }
        op[j / 4] = make_float4(s0, s1, s2, s3);
    }
}

// ===================== launch =====================

extern "C" void kernel_launch(void* const* d_in, const int* in_sizes, int n_in,
                              void* d_out, int out_size, void* d_ws, size_t ws_size,
                              hipStream_t stream) {
    const float* left   = (const float*)d_in[0];
    const int*   eidx   = (const int*)d_in[2];
    const float* ew     = (const float*)d_in[3];
    const float* right  = (const float*)d_in[4];
    const float* c      = (const float*)d_in[5];
    const float* temp   = (const float*)d_in[7];
    const float* W1     = (const float*)d_in[8];
    const float* b1     = (const float*)d_in[9];
    const float* W2     = (const float*)d_in[10];
    const float* b2     = (const float*)d_in[11];

    const int n_edges = in_sizes[3];
    const int n_right = in_sizes[4] / EMB;
    const int n_left  = in_sizes[0] / EMB;
    float* out = (float*)d_out;

    const int nb = (n_right + BROWS - 1) >> BSHIFT;

    // ws layout
    size_t off_bbase   = 64;                                         // total at 0
    size_t off_bcursor = (off_bbase + (size_t)(nb + 1) * 4 + 255) & ~(size_t)255;
    size_t off_sorted  = (off_bcursor + (size_t)nb * 4 + 255) & ~(size_t)255;
    size_t off_left16  = (off_sorted + (size_t)n_edges * 8 + 255) & ~(size_t)255;
    size_t required    = off_left16 + (size_t)n_left * EMB * 2;

    if (ws_size >= required && nb <= 256 && n_left <= (1 << COLBITS)) {
        char* ws = (char*)d_ws;
        float* total = (float*)ws;
        int* bbase = (int*)(ws + off_bbase);
        int* bcursor = (int*)(ws + off_bcursor);
        int2* sorted = (int2*)(ws + off_sorted);
        unsigned short* left16 = (unsigned short*)(ws + off_left16);

        // zero total + bucket counts
        hipMemsetAsync(ws, 0, off_bbase + (size_t)(nb + 1) * 4, stream);

        {
            int n2 = n_left * EMB / 2;
            convert_left_kernel<<<(n2 + 255) / 256, 256, 0, stream>>>(
                left, (unsigned*)left16, n2);
        }
        hist_total_kernel<<<512, 256, 0, stream>>>((const int2*)eidx, ew, n_edges,
                                                   nb, bbase, total);
        bucket_scan_kernel<<<1, 256, 0, stream>>>(bbase, bcursor, nb, n_edges);
        {
            int nchunks = (n_edges + CHUNK - 1) / CHUNK;
            partition_kernel<<<nchunks, 256, 0, stream>>>(
                (const int2*)eidx, ew, n_edges, nb, bcursor, sorted);
        }
        bucket_accum_kernel<<<nb, 1024, BROWS * EMB * 4, stream>>>(
            sorted, bbase, left16, right, c, temp, total, out, n_right);
        {
            int blocks = (n_right + 255) / 256;
            mlp_kernel<<<blocks, 256, 0, stream>>>(W1, b1, W2, b2, out, n_right);
        }
    } else {
        // fallback: atomic path
        float* total = (float*)d_ws;
        hipMemsetAsync(d_out, 0, (size_t)out_size * sizeof(float), stream);
        hipMemsetAsync(d_ws, 0, sizeof(float), stream);
        sum_weights_kernel<<<2048, 256, 0, stream>>>(ew, n_edges, total);
        long long n_threads = (long long)n_edges * EMB;
        long long blocks = (n_threads + 255) / 256;
        edge_scatter_kernel<<<(int)blocks, 256, 0, stream>>>(
            eidx, ew, left, total, out, n_threads);
        int mblocks = (n_right + 255) / 256;
        fused_mlp_kernel<<<mblocks, 256, 0, stream>>>(right, c, temp, W1, b1, W2,
                                                      b2, out, n_right);
    }
}

// Round 5
// 460.123 us; speedup vs baseline: 3.3278x; 3.3278x over previous
//
#include <hip/hip_runtime.h>

#define EMB 64
#define BROWS 512            // rows per bucket
#define BSHIFT 9             // log2(BROWS)
#define CHUNK 4096           // edges per partition block
#define COLBITS 23
#define COLMASK ((1u << COLBITS) - 1u)

// bf16 helpers (manual RNE pack/unpack)
__device__ __forceinline__ unsigned short f2bf(float f) {
    unsigned u = __float_as_uint(f);
    u = u + 0x7FFFu + ((u >> 16) & 1u);
    return (unsigned short)(u >> 16);
}
__device__ __forceinline__ float bf2f(unsigned short s) {
    return __uint_as_float(((unsigned)s) << 16);
}

// K0: convert left (f32) -> left16 (bf16), 2 elems/thread
__global__ void convert_left_kernel(const float* __restrict__ left,
                                    unsigned* __restrict__ left16, int n2) {
    int i = blockIdx.x * blockDim.x + threadIdx.x;
    if (i >= n2) return;
    float2 v = ((const float2*)left)[i];
    left16[i] = (unsigned)f2bf(v.x) | ((unsigned)f2bf(v.y) << 16);
}

// K1: counts[row]++ over edges, and total = sum(edge_weight)
__global__ void hist_total_kernel(const int2* __restrict__ eidx,
                                  const float* __restrict__ w, int n_edges,
                                  int* __restrict__ counts,
                                  float* __restrict__ total) {
    int gid = blockIdx.x * blockDim.x + threadIdx.x;
    int stride = gridDim.x * blockDim.x;
    float s = 0.f;
    for (int e = gid; e < n_edges; e += stride) {
        s += w[e];
        atomicAdd(&counts[eidx[e].x], 1);
    }
    #pragma unroll
    for (int off = 32; off > 0; off >>= 1) s += __shfl_down(s, off, 64);
    if ((threadIdx.x & 63) == 0) atomicAdd(total, s);
}

// K2a: per-1024-tile inclusive scan; tile sums to bsums
__global__ __launch_bounds__(1024, 1) void scan1_kernel(
    const int* __restrict__ cnt, int* __restrict__ incl,
    int* __restrict__ bsums, int n) {
    __shared__ int s[1024];
    int t = threadIdx.x;
    int i = blockIdx.x * 1024 + t;
    int v = (i < n) ? cnt[i] : 0;
    s[t] = v;
    __syncthreads();
    for (int off = 1; off < 1024; off <<= 1) {
        int u = (t >= off) ? s[t - off] : 0;
        __syncthreads();
        s[t] += u;
        __syncthreads();
    }
    if (i < n) incl[i] = s[t];
    if (t == 1023) bsums[blockIdx.x] = s[t];
}

// K2b: exclusive scan of block sums (single block, nb <= 256)
__global__ __launch_bounds__(256, 1) void scan2_kernel(int* __restrict__ bsums, int nb) {
    __shared__ int s[256];
    int t = threadIdx.x;
    int v = (t < nb) ? bsums[t] : 0;
    s[t] = v;
    __syncthreads();
    for (int off = 1; off < 256; off <<= 1) {
        int u = (t >= off) ? s[t - off] : 0;
        __syncthreads();
        s[t] += u;
        __syncthreads();
    }
    if (t < nb) bsums[t] = s[t] - v;  // exclusive base
}

// K2c: offs[i] = exclusive global scan (segment STARTS)
__global__ void scan3_kernel(const int* __restrict__ incl,
                             const int* __restrict__ base,
                             int* __restrict__ offs, int n) {
    int i = blockIdx.x * blockDim.x + threadIdx.x;
    if (i >= n) return;
    offs[i] = (i == 0) ? 0 : incl[i - 1] + base[(i - 1) >> 10];
}

// K2d: bcursor[b] = offs[b << BSHIFT]
__global__ void init_bcursor_kernel(const int* __restrict__ offs,
                                    int* __restrict__ bcursor, int nb) {
    int b = blockIdx.x * blockDim.x + threadIdx.x;
    if (b < nb) bcursor[b] = offs[b << BSHIFT];
}

// K3: partition edges into buckets with LDS staging for coalesced writes.
// bsorted[i] = ( (row_local << COLBITS) | col , bits(w) ), bucket-contiguous.
__global__ __launch_bounds__(256) void partition_kernel(
    const int2* __restrict__ eidx, const float* __restrict__ w, int n_edges,
    int nb, int* __restrict__ bcursor, int2* __restrict__ bsorted) {
    __shared__ int lh[256];
    __shared__ int lo[256];
    __shared__ int go[256];
    __shared__ int lcur[256];
    __shared__ int2 stage[CHUNK];
    __shared__ int dstg[CHUNK];
    int t = threadIdx.x;
    int base = blockIdx.x * CHUNK;
    int cnt = min(CHUNK, n_edges - base);

    lh[t] = 0;
    __syncthreads();
    #pragma unroll
    for (int k = 0; k < CHUNK / 256; ++k) {
        int e = base + t + k * 256;
        if (e < n_edges) atomicAdd(&lh[eidx[e].x >> BSHIFT], 1);
    }
    __syncthreads();
    int v = lh[t];
    lo[t] = v;
    __syncthreads();
    for (int off = 1; off < 256; off <<= 1) {
        int u = (t >= off) ? lo[t - off] : 0;
        __syncthreads();
        lo[t] += u;
        __syncthreads();
    }
    int excl = lo[t] - v;
    go[t] = (v > 0) ? atomicAdd(&bcursor[t], v) : 0;
    __syncthreads();
    lo[t] = excl;
    lcur[t] = excl;
    __syncthreads();

    #pragma unroll
    for (int k = 0; k < CHUNK / 256; ++k) {
        int e = base + t + k * 256;
        if (e < n_edges) {
            int2 rc = eidx[e];
            float wv = w[e];
            int b = rc.x >> BSHIFT;
            unsigned rl = (unsigned)(rc.x & (BROWS - 1));
            int p = atomicAdd(&lcur[b], 1);
            stage[p] = make_int2((int)((rl << COLBITS) | (unsigned)rc.y),
                                 __float_as_int(wv));
            dstg[p] = go[b] + (p - lo[b]);
        }
    }
    __syncthreads();
    #pragma unroll
    for (int k = 0; k < CHUNK / 256; ++k) {
        int s = t + k * 256;
        if (s < cnt) bsorted[dstg[s]] = stage[s];
    }
}

// K3b: one block per bucket; scatter bucket edges to exact per-row positions.
// LDS row cursors (init from offs). Writes random only within the bucket's
// ~131KB window -> L2-local, no cross-XCD write amplification.
__global__ __launch_bounds__(256) void local_scatter_kernel(
    const int2* __restrict__ bsorted, const int* __restrict__ offs,
    int n_right, int n_edges, int2* __restrict__ sorted2) {
    __shared__ int lcur[BROWS];
    int b = blockIdx.x;
    int t = threadIdx.x;
    int row0 = b << BSHIFT;
    int nrows = min(BROWS, n_right - row0);
    for (int r = t; r < nrows; r += 256) lcur[r] = offs[row0 + r];
    __syncthreads();
    int start = offs[row0];
    int r2 = row0 + nrows;
    int end = (r2 < n_right) ? offs[r2] : n_edges;

    int e = start + t;
    for (; e + 3 * 256 < end; e += 4 * 256) {
        int2 v0 = bsorted[e + 0 * 256];
        int2 v1 = bsorted[e + 1 * 256];
        int2 v2 = bsorted[e + 2 * 256];
        int2 v3 = bsorted[e + 3 * 256];
        int p0 = atomicAdd(&lcur[((unsigned)v0.x) >> COLBITS], 1);
        int p1 = atomicAdd(&lcur[((unsigned)v1.x) >> COLBITS], 1);
        int p2 = atomicAdd(&lcur[((unsigned)v2.x) >> COLBITS], 1);
        int p3 = atomicAdd(&lcur[((unsigned)v3.x) >> COLBITS], 1);
        sorted2[p0] = v0;
        sorted2[p1] = v1;
        sorted2[p2] = v2;
        sorted2[p3] = v3;
    }
    for (; e < end; e += 256) {
        int2 v0 = bsorted[e];
        int p0 = atomicAdd(&lcur[((unsigned)v0.x) >> COLBITS], 1);
        sorted2[p0] = v0;
    }
}

// K4: one wave per row (bf16 gathers): h = right + t1*(c - conv/total)
// offs_are_ends=false: offs[r]=start, end=offs[r+1] (or n_edges)
// offs_are_ends=true : offs[r]=end,   start=offs[r-1] (or 0)   [mid path]
__global__ void seg_gather_bf16_kernel(const int2* __restrict__ sorted,
                                       const int* __restrict__ offs,
                                       const unsigned short* __restrict__ left16,
                                       const float* __restrict__ right,
                                       const float* __restrict__ c,
                                       const float* __restrict__ temp,
                                       const float* __restrict__ total,
                                       float* __restrict__ hout, int n_right,
                                       int n_edges, int offs_are_ends) {
    int gid = blockIdx.x * blockDim.x + threadIdx.x;
    int wid = gid >> 6;
    int lane = gid & 63;
    if (wid >= n_right) return;
    int start, end;
    if (offs_are_ends) {
        end = offs[wid];
        start = (wid == 0) ? 0 : offs[wid - 1];
    } else {
        start = offs[wid];
        end = (wid + 1 < n_right) ? offs[wid + 1] : n_edges;
    }

    float a0 = 0.f, a1 = 0.f, a2 = 0.f, a3 = 0.f;
    int e = start;
    for (; e + 4 <= end; e += 4) {
        int2 c0 = sorted[e + 0];
        int2 c1 = sorted[e + 1];
        int2 c2 = sorted[e + 2];
        int2 c3 = sorted[e + 3];
        a0 = fmaf(__int_as_float(c0.y),
                  bf2f(left16[(size_t)((unsigned)c0.x & COLMASK) * EMB + lane]), a0);
        a1 = fmaf(__int_as_float(c1.y),
                  bf2f(left16[(size_t)((unsigned)c1.x & COLMASK) * EMB + lane]), a1);
        a2 = fmaf(__int_as_float(c2.y),
                  bf2f(left16[(size_t)((unsigned)c2.x & COLMASK) * EMB + lane]), a2);
        a3 = fmaf(__int_as_float(c3.y),
                  bf2f(left16[(size_t)((unsigned)c3.x & COLMASK) * EMB + lane]), a3);
    }
    for (; e < end; ++e) {
        int2 cc = sorted[e];
        a0 = fmaf(__int_as_float(cc.y),
                  bf2f(left16[(size_t)((unsigned)cc.x & COLMASK) * EMB + lane]), a0);
    }
    float conv = (a0 + a1) + (a2 + a3);
    float inv = 1.0f / fmaxf(total[0], 1.0f);
    float t1 = temp[1];
    float h = right[(size_t)wid * EMB + lane] + t1 * (c[wid] - conv * inv);
    hout[(size_t)wid * EMB + lane] = h;
}

// mid path: direct scatter (mutates offs starts -> ends)
__global__ void scatter_kernel(const int2* __restrict__ eidx,
                               const float* __restrict__ w, int n_edges,
                               int* __restrict__ offs,
                               int2* __restrict__ sorted) {
    int gid = blockIdx.x * blockDim.x + threadIdx.x;
    int stride = gridDim.x * blockDim.x;
    for (int e = gid; e < n_edges; e += stride) {
        int2 rc = eidx[e];
        float v = w[e];
        int pos = atomicAdd(&offs[rc.x], 1);
        sorted[pos] = make_int2(rc.y, __float_as_int(v));
    }
}

// K5: MLP on h (in place in io): out = relu(h@W1^T+b1)@W2^T+b2
__global__ __launch_bounds__(256, 1) void mlp_kernel(
    const float* __restrict__ W1, const float* __restrict__ b1,
    const float* __restrict__ W2, const float* __restrict__ b2,
    float* __restrict__ io, int n) {
    int r = blockIdx.x * blockDim.x + threadIdx.x;
    if (r >= n) return;

    float h[EMB];
    const float4* qp = (const float4*)(io + (size_t)r * EMB);
    #pragma unroll
    for (int q = 0; q < EMB / 4; ++q) {
        float4 qv = qp[q];
        h[4 * q + 0] = qv.x;
        h[4 * q + 1] = qv.y;
        h[4 * q + 2] = qv.z;
        h[4 * q + 3] = qv.w;
    }

    float h1[EMB];
    #pragma unroll
    for (int j = 0; j < EMB; j += 4) {
        float s0 = b1[j + 0], s1 = b1[j + 1], s2 = b1[j + 2], s3 = b1[j + 3];
        #pragma unroll
        for (int k = 0; k < EMB; ++k) {
            float hk = h[k];
            s0 = fmaf(hk, W1[(j + 0) * EMB + k], s0);
            s1 = fmaf(hk, W1[(j + 1) * EMB + k], s1);
            s2 = fmaf(hk, W1[(j + 2) * EMB + k], s2);
            s3 = fmaf(hk, W1[(j + 3) * EMB + k], s3);
        }
        h1[j + 0] = fmaxf(s0, 0.f);
        h1[j + 1] = fmaxf(s1, 0.f);
        h1[j + 2] = fmaxf(s2, 0.f);
        h1[j + 3] = fmaxf(s3, 0.f);
    }

    float4* op = (float4*)(io + (size_t)r * EMB);
    #pragma unroll
    for (int j = 0; j < EMB; j += 4) {
        float s0 = b2[j + 0], s1 = b2[j + 1], s2 = b2[j + 2], s3 = b2[j + 3];
        #pragma unroll
        for (int k = 0; k < EMB; ++k) {
            float hk = h1[k];
            s0 = fmaf(hk, W2[(j + 0) * EMB + k], s0);
            s1 = fmaf(hk, W2[(j + 1) * EMB + k], s1);
            s2 = fmaf(hk, W2[(j + 2) * EMB + k], s2);
            s3 = fmaf(hk, W2[(j + 3) * EMB + k], s3);
        }
        op[j / 4] = make_float4(s0, s1, s2, s3);
    }
}

// ===================== fallback (atomic path) =====================

__global__ void sum_weights_kernel(const float* __restrict__ w, int n,
                                   float* __restrict__ total) {
    int gid = blockIdx.x * blockDim.x + threadIdx.x;
    int stride = gridDim.x * blockDim.x;
    float s = 0.f;
    for (int i = gid; i < n; i += stride) s += w[i];
    #pragma unroll
    for (int off = 32; off > 0; off >>= 1) s += __shfl_down(s, off, 64);
    if ((threadIdx.x & 63) == 0) atomicAdd(total, s);
}

__global__ void edge_scatter_kernel(const int* __restrict__ idx,
                                    const float* __restrict__ w,
                                    const float* __restrict__ left,
                                    const float* __restrict__ total,
                                    float* __restrict__ conv,
                                    long long n_threads) {
    long long gid = (long long)blockIdx.x * blockDim.x + threadIdx.x;
    if (gid >= n_threads) return;
    int e = (int)(gid >> 6);
    int d = (int)(gid & 63);
    float inv = 1.0f / fmaxf(total[0], 1.0f);
    int row = idx[2 * e];
    int col = idx[2 * e + 1];
    float v = w[e] * inv;
    float msg = left[(size_t)col * EMB + d] * v;
    atomicAdd(&conv[(size_t)row * EMB + d], msg);
}

__global__ __launch_bounds__(256, 1) void fused_mlp_kernel(
    const float* __restrict__ right, const float* __restrict__ c,
    const float* __restrict__ temp,
    const float* __restrict__ W1, const float* __restrict__ b1,
    const float* __restrict__ W2, const float* __restrict__ b2,
    float* __restrict__ io, int n) {
    int r = blockIdx.x * blockDim.x + threadIdx.x;
    if (r >= n) return;
    float t1 = temp[1];
    float cv = c[r];
    float h[EMB];
    const float4* rp = (const float4*)(right + (size_t)r * EMB);
    const float4* qp = (const float4*)(io + (size_t)r * EMB);
    #pragma unroll
    for (int q = 0; q < EMB / 4; ++q) {
        float4 rv = rp[q];
        float4 qv = qp[q];
        h[4 * q + 0] = rv.x + t1 * (cv - qv.x);
        h[4 * q + 1] = rv.y + t1 * (cv - qv.y);
        h[4 * q + 2] = rv.z + t1 * (cv - qv.z);
        h[4 * q + 3] = rv.w + t1 * (cv - qv.w);
    }
    float h1[EMB];
    #pragma unroll
    for (int j = 0; j < EMB; j += 4) {
        float s0 = b1[j], s1 = b1[j + 1], s2 = b1[j + 2], s3 = b1[j + 3];
        #pragma unroll
        for (int k = 0; k < EMB; ++k) {
            float hk = h[k];
            s0 = fmaf(hk, W1[(j + 0) * EMB + k], s0);
            s1 = fmaf(hk, W1[(j + 1) * EMB + k], s1);
            s2 = fmaf(hk, W1[(j + 2) * EMB + k], s2);
            s3 = fmaf(hk, W1[(j + 3) * EMB + k], s3);
        }
        h1[j] = fmaxf(s0, 0.f);
        h1[j + 1] = fmaxf(s1, 0.f);
        h1[j + 2] = fmaxf(s2, 0.f);
        h1[j + 3] = fmaxf(s3, 0.f);
    }
    float4* op = (float4*)(io + (size_t)r * EMB);
    #pragma unroll
    for (int j = 0; j < EMB; j += 4) {
        float s0 = b2[j], s1 = b2[j + 1], s2 = b2[j + 2], s3 = b2[j + 3];
        #pragma unroll
        for (int k = 0; k < EMB; ++k) {
            float hk = h1[k];
            s0 = fmaf(hk, W2[(j + 0) * EMB + k], s0);
            s1 = fmaf(hk, W2[(j + 1) * EMB + k], s1);
            s2 = fmaf(hk, W2[(j + 2) * EMB + k], s2);
            s3 = fmaf(hk, W2[(j + 3) * EMB + k], s3);
        }
        op[j / 4] = make_float4(s0, s1, s2, s3);
    }
}

// ===================== launch =====================

extern "C" void kernel_launch(void* const* d_in, const int* in_sizes, int n_in,
                              void* d_out, int out_size, void* d_ws, size_t ws_size,
                              hipStream_t stream) {
    const float* left   = (const float*)d_in[0];
    const int*   eidx   = (const int*)d_in[2];
    const float* ew     = (const float*)d_in[3];
    const float* right  = (const float*)d_in[4];
    const float* c      = (const float*)d_in[5];
    const float* temp   = (const float*)d_in[7];
    const float* W1     = (const float*)d_in[8];
    const float* b1     = (const float*)d_in[9];
    const float* W2     = (const float*)d_in[10];
    const float* b2     = (const float*)d_in[11];

    const int n_edges = in_sizes[3];
    const int n_right = in_sizes[4] / EMB;
    const int n_left  = in_sizes[0] / EMB;
    float* out = (float*)d_out;

    const int nb = (n_right + BROWS - 1) >> BSHIFT;
    const int nblocks_scan = (n_right + 1023) / 1024;

    auto align256 = [](size_t x) { return (x + 255) & ~(size_t)255; };

    // common prefix
    size_t off_offs = 64;
    size_t off_incl = align256(off_offs + (size_t)n_right * 4);
    size_t off_bsum = align256(off_incl + (size_t)n_right * 4);
    size_t off_bcur = align256(off_bsum + 1024);
    size_t off_bsorted = align256(off_bcur + (size_t)nb * 4);
    size_t off_sorted2 = align256(off_bsorted + (size_t)n_edges * 8);
    size_t off_left16_full = align256(off_sorted2 + (size_t)n_edges * 8);
    size_t req_full = off_left16_full + (size_t)n_left * EMB * 2;
    // mid path reuses bsorted slot as the single sorted buffer
    size_t off_left16_mid = off_sorted2;
    size_t req_mid = off_left16_mid + (size_t)n_left * EMB * 2;

    bool common_ok = (nb <= 256) && (nblocks_scan <= 256) &&
                     (n_left <= (1 << COLBITS)) && (BROWS * nb >= n_right);

    if (common_ok && ws_size >= req_full) {
        // ---------- full path: partition + local scatter ----------
        char* ws = (char*)d_ws;
        float* total = (float*)ws;
        int* offs = (int*)(ws + off_offs);
        int* incl = (int*)(ws + off_incl);
        int* bsum = (int*)(ws + off_bsum);
        int* bcur = (int*)(ws + off_bcur);
        int2* bsorted = (int2*)(ws + off_bsorted);
        int2* sorted2 = (int2*)(ws + off_sorted2);
        unsigned short* left16 = (unsigned short*)(ws + off_left16_full);

        hipMemsetAsync(ws, 0, off_offs + (size_t)n_right * 4, stream);

        int n2 = n_left * EMB / 2;
        convert_left_kernel<<<(n2 + 255) / 256, 256, 0, stream>>>(
            left, (unsigned*)left16, n2);
        hist_total_kernel<<<2048, 256, 0, stream>>>((const int2*)eidx, ew,
                                                    n_edges, offs, total);
        scan1_kernel<<<nblocks_scan, 1024, 0, stream>>>(offs, incl, bsum, n_right);
        scan2_kernel<<<1, 256, 0, stream>>>(bsum, nblocks_scan);
        scan3_kernel<<<(n_right + 255) / 256, 256, 0, stream>>>(incl, bsum, offs,
                                                                n_right);
        init_bcursor_kernel<<<(nb + 255) / 256, 256, 0, stream>>>(offs, bcur, nb);
        {
            int nchunks = (n_edges + CHUNK - 1) / CHUNK;
            partition_kernel<<<nchunks, 256, 0, stream>>>(
                (const int2*)eidx, ew, n_edges, nb, bcur, bsorted);
        }
        local_scatter_kernel<<<nb, 256, 0, stream>>>(bsorted, offs, n_right,
                                                     n_edges, sorted2);
        {
            long long n_threads = (long long)n_right * EMB;
            int blocks = (int)((n_threads + 255) / 256);
            seg_gather_bf16_kernel<<<blocks, 256, 0, stream>>>(
                sorted2, offs, left16, right, c, temp, total, out, n_right,
                n_edges, 0);
        }
        mlp_kernel<<<(n_right + 255) / 256, 256, 0, stream>>>(W1, b1, W2, b2,
                                                              out, n_right);
    } else if (common_ok && ws_size >= req_mid) {
        // ---------- mid path: round-3 proven structure ----------
        char* ws = (char*)d_ws;
        float* total = (float*)ws;
        int* offs = (int*)(ws + off_offs);
        int* incl = (int*)(ws + off_incl);
        int* bsum = (int*)(ws + off_bsum);
        int2* sorted = (int2*)(ws + off_bsorted);
        unsigned short* left16 = (unsigned short*)(ws + off_left16_mid);

        hipMemsetAsync(ws, 0, off_offs + (size_t)n_right * 4, stream);

        int n2 = n_left * EMB / 2;
        convert_left_kernel<<<(n2 + 255) / 256, 256, 0, stream>>>(
            left, (unsigned*)left16, n2);
        hist_total_kernel<<<2048, 256, 0, stream>>>((const int2*)eidx, ew,
                                                    n_edges, offs, total);
        scan1_kernel<<<nblocks_scan, 1024, 0, stream>>>(offs, incl, bsum, n_right);
        scan2_kernel<<<1, 256, 0, stream>>>(bsum, nblocks_scan);
        scan3_kernel<<<(n_right + 255) / 256, 256, 0, stream>>>(incl, bsum, offs,
                                                                n_right);
        scatter_kernel<<<2048, 256, 0, stream>>>((const int2*)eidx, ew, n_edges,
                                                 offs, sorted);
        {
            long long n_threads = (long long)n_right * EMB;
            int blocks = (int)((n_threads + 255) / 256);
            seg_gather_bf16_kernel<<<blocks, 256, 0, stream>>>(
                sorted, offs, left16, right, c, temp, total, out, n_right,
                n_edges, 1);
        }
        mlp_kernel<<<(n_right + 255) / 256, 256, 0, stream>>>(W1, b1, W2, b2,
                                                              out, n_right);
    } else {
        // ---------- fallback: atomic path ----------
        float* total = (float*)d_ws;
        hipMemsetAsync(d_out, 0, (size_t)out_size * sizeof(float), stream);
        hipMemsetAsync(d_ws, 0, sizeof(float), stream);
        sum_weights_kernel<<<2048, 256, 0, stream>>>(ew, n_edges, total);
        long long n_threads = (long long)n_edges * EMB;
        long long blocks = (n_threads + 255) / 256;
        edge_scatter_kernel<<<(int)blocks, 256, 0, stream>>>(
            eidx, ew, left, total, out, n_threads);
        int mblocks = (n_right + 255) / 256;
        fused_mlp_kernel<<<mblocks, 256, 0, stream>>>(right, c, temp, W1, b1, W2,
                                                      b2, out, n_right);
    }
}

// Round 6
// 332.751 us; speedup vs baseline: 4.6016x; 1.3828x over previous
//
#include <hip/hip_runtime.h>

#define EMB 64
#define BROWS 512            // rows per bucket
#define BSHIFT 9             // log2(BROWS)
#define CHUNK 4096           // edges per partition block
#define COLBITS 23
#define COLMASK ((1u << COLBITS) - 1u)

// bf16 helpers (manual RNE pack/unpack)
__device__ __forceinline__ unsigned short f2bf(float f) {
    unsigned u = __float_as_uint(f);
    u = u + 0x7FFFu + ((u >> 16) & 1u);
    return (unsigned short)(u >> 16);
}
__device__ __forceinline__ float bf2f(unsigned short s) {
    return __uint_as_float(((unsigned)s) << 16);
}

// K0: convert left (f32) -> left16 (bf16), 2 elems/thread
__global__ void convert_left_kernel(const float* __restrict__ left,
                                    unsigned* __restrict__ left16, int n2) {
    int i = blockIdx.x * blockDim.x + threadIdx.x;
    if (i >= n2) return;
    float2 v = ((const float2*)left)[i];
    left16[i] = (unsigned)f2bf(v.x) | ((unsigned)f2bf(v.y) << 16);
}

// K1: LDS-aggregated bucket histogram (nb<=256 bins) + total = sum(w)
__global__ __launch_bounds__(256) void bucket_hist_kernel(
    const int2* __restrict__ eidx, const float* __restrict__ w, int n_edges,
    int nb, int* __restrict__ bcount, float* __restrict__ total) {
    __shared__ int lh[256];
    int t = threadIdx.x;
    lh[t] = 0;
    __syncthreads();
    int gid = blockIdx.x * 256 + t;
    int stride = gridDim.x * 256;
    float s = 0.f;
    for (int e = gid; e < n_edges; e += stride) {
        s += w[e];
        atomicAdd(&lh[eidx[e].x >> BSHIFT], 1);
    }
    #pragma unroll
    for (int off = 32; off > 0; off >>= 1) s += __shfl_down(s, off, 64);
    if ((t & 63) == 0) atomicAdd(total, s);
    __syncthreads();
    if (t < nb && lh[t]) atomicAdd(&bcount[t], lh[t]);
}

// K2: single-block exclusive scan of bucket counts (nb <= 256), in place.
// bbase[b] = exclusive offset; bcursor[b] = copy; bbase[nb] = n_edges
__global__ __launch_bounds__(256, 1) void bucket_scan_kernel(
    int* __restrict__ bbase, int* __restrict__ bcursor, int nb, int n_edges) {
    __shared__ int ssc[256];
    int t = threadIdx.x;
    int v = (t < nb) ? bbase[t] : 0;
    ssc[t] = v;
    __syncthreads();
    for (int off = 1; off < 256; off <<= 1) {
        int u = (t >= off) ? ssc[t - off] : 0;
        __syncthreads();
        ssc[t] += u;
        __syncthreads();
    }
    int excl = ssc[t] - v;
    if (t < nb) { bbase[t] = excl; bcursor[t] = excl; }
    if (t == 0) bbase[nb] = n_edges;
}

// K3: partition edges into buckets with LDS staging for coalesced writes.
// bsorted[i] = ( (row_local << COLBITS) | col , bits(w) ), bucket-contiguous.
__global__ __launch_bounds__(256) void partition_kernel(
    const int2* __restrict__ eidx, const float* __restrict__ w, int n_edges,
    int nb, int* __restrict__ bcursor, int2* __restrict__ bsorted) {
    __shared__ int lh[256];
    __shared__ int lo[256];
    __shared__ int go[256];
    __shared__ int lcur[256];
    __shared__ int2 stage[CHUNK];
    __shared__ int dstg[CHUNK];
    int t = threadIdx.x;
    int base = blockIdx.x * CHUNK;
    int cnt = min(CHUNK, n_edges - base);

    lh[t] = 0;
    __syncthreads();
    #pragma unroll
    for (int k = 0; k < CHUNK / 256; ++k) {
        int e = base + t + k * 256;
        if (e < n_edges) atomicAdd(&lh[eidx[e].x >> BSHIFT], 1);
    }
    __syncthreads();
    int v = lh[t];
    lo[t] = v;
    __syncthreads();
    for (int off = 1; off < 256; off <<= 1) {
        int u = (t >= off) ? lo[t - off] : 0;
        __syncthreads();
        lo[t] += u;
        __syncthreads();
    }
    int excl = lo[t] - v;
    go[t] = (v > 0) ? atomicAdd(&bcursor[t], v) : 0;
    __syncthreads();
    lo[t] = excl;
    lcur[t] = excl;
    __syncthreads();

    #pragma unroll
    for (int k = 0; k < CHUNK / 256; ++k) {
        int e = base + t + k * 256;
        if (e < n_edges) {
            int2 rc = eidx[e];
            float wv = w[e];
            int b = rc.x >> BSHIFT;
            unsigned rl = (unsigned)(rc.x & (BROWS - 1));
            int p = atomicAdd(&lcur[b], 1);
            stage[p] = make_int2((int)((rl << COLBITS) | (unsigned)rc.y),
                                 __float_as_int(wv));
            dstg[p] = go[b] + (p - lo[b]);
        }
    }
    __syncthreads();
    #pragma unroll
    for (int k = 0; k < CHUNK / 256; ++k) {
        int s = t + k * 256;
        if (s < cnt) bsorted[dstg[s]] = stage[s];
    }
}

// K3b: one block per bucket. Builds per-row offsets IN LDS (512-bin hist +
// scan), writes offs[row] (coalesced), then scatters the bucket's edges into
// exact row-sorted positions (random only within the bucket's L2-local window).
__global__ __launch_bounds__(256) void local_rowsort_kernel(
    const int2* __restrict__ bsorted, const int* __restrict__ bbase,
    int* __restrict__ offs, int2* __restrict__ sorted2, int n_right) {
    __shared__ int lhist[BROWS];
    __shared__ int lcur[BROWS];
    __shared__ int ps[256];
    int b = blockIdx.x;
    int t = threadIdx.x;
    int start = bbase[b];
    int end = bbase[b + 1];
    int row0 = b << BSHIFT;
    int nrows = min(BROWS, n_right - row0);

    lhist[2 * t] = 0;
    lhist[2 * t + 1] = 0;
    __syncthreads();
    for (int e = start + t; e < end; e += 256)
        atomicAdd(&lhist[((unsigned)bsorted[e].x) >> COLBITS], 1);
    __syncthreads();

    // exclusive scan of 512 bins with 256 threads (pair trick)
    int v0 = lhist[2 * t];
    int v1 = lhist[2 * t + 1];
    int pv = v0 + v1;
    ps[t] = pv;
    __syncthreads();
    for (int off = 1; off < 256; off <<= 1) {
        int u = (t >= off) ? ps[t - off] : 0;
        __syncthreads();
        ps[t] += u;
        __syncthreads();
    }
    int epair = ps[t] - pv;          // exclusive pair base (local)
    lcur[2 * t] = epair;
    lcur[2 * t + 1] = epair + v0;
    if (2 * t < nrows)     offs[row0 + 2 * t]     = start + epair;
    if (2 * t + 1 < nrows) offs[row0 + 2 * t + 1] = start + epair + v0;
    __syncthreads();

    // scatter into exact row positions
    int e = start + t;
    for (; e + 3 * 256 < end; e += 4 * 256) {
        int2 e0 = bsorted[e + 0 * 256];
        int2 e1 = bsorted[e + 1 * 256];
        int2 e2 = bsorted[e + 2 * 256];
        int2 e3 = bsorted[e + 3 * 256];
        int p0 = atomicAdd(&lcur[((unsigned)e0.x) >> COLBITS], 1);
        int p1 = atomicAdd(&lcur[((unsigned)e1.x) >> COLBITS], 1);
        int p2 = atomicAdd(&lcur[((unsigned)e2.x) >> COLBITS], 1);
        int p3 = atomicAdd(&lcur[((unsigned)e3.x) >> COLBITS], 1);
        sorted2[start + p0] = e0;
        sorted2[start + p1] = e1;
        sorted2[start + p2] = e2;
        sorted2[start + p3] = e3;
    }
    for (; e < end; e += 256) {
        int2 e0 = bsorted[e];
        int p0 = atomicAdd(&lcur[((unsigned)e0.x) >> COLBITS], 1);
        sorted2[start + p0] = e0;
    }
}

// K4: one wave per row (bf16 gathers): h = right + t1*(c - conv/total)
// offs_are_ends=false: offs[r]=start, end=offs[r+1] (or n_edges)
// offs_are_ends=true : offs[r]=end,   start=offs[r-1] (or 0)   [mid path]
__global__ void seg_gather_bf16_kernel(const int2* __restrict__ sorted,
                                       const int* __restrict__ offs,
                                       const unsigned short* __restrict__ left16,
                                       const float* __restrict__ right,
                                       const float* __restrict__ c,
                                       const float* __restrict__ temp,
                                       const float* __restrict__ total,
                                       float* __restrict__ hout, int n_right,
                                       int n_edges, int offs_are_ends) {
    int gid = blockIdx.x * blockDim.x + threadIdx.x;
    int wid = gid >> 6;
    int lane = gid & 63;
    if (wid >= n_right) return;
    int start, end;
    if (offs_are_ends) {
        end = offs[wid];
        start = (wid == 0) ? 0 : offs[wid - 1];
    } else {
        start = offs[wid];
        end = (wid + 1 < n_right) ? offs[wid + 1] : n_edges;
    }

    float a0 = 0.f, a1 = 0.f, a2 = 0.f, a3 = 0.f;
    int e = start;
    for (; e + 4 <= end; e += 4) {
        int2 c0 = sorted[e + 0];
        int2 c1 = sorted[e + 1];
        int2 c2 = sorted[e + 2];
        int2 c3 = sorted[e + 3];
        a0 = fmaf(__int_as_float(c0.y),
                  bf2f(left16[(size_t)((unsigned)c0.x & COLMASK) * EMB + lane]), a0);
        a1 = fmaf(__int_as_float(c1.y),
                  bf2f(left16[(size_t)((unsigned)c1.x & COLMASK) * EMB + lane]), a1);
        a2 = fmaf(__int_as_float(c2.y),
                  bf2f(left16[(size_t)((unsigned)c2.x & COLMASK) * EMB + lane]), a2);
        a3 = fmaf(__int_as_float(c3.y),
                  bf2f(left16[(size_t)((unsigned)c3.x & COLMASK) * EMB + lane]), a3);
    }
    for (; e < end; ++e) {
        int2 cc = sorted[e];
        a0 = fmaf(__int_as_float(cc.y),
                  bf2f(left16[(size_t)((unsigned)cc.x & COLMASK) * EMB + lane]), a0);
    }
    float conv = (a0 + a1) + (a2 + a3);
    float inv = 1.0f / fmaxf(total[0], 1.0f);
    float t1 = temp[1];
    float h = right[(size_t)wid * EMB + lane] + t1 * (c[wid] - conv * inv);
    hout[(size_t)wid * EMB + lane] = h;
}

// K5: MLP on h (in place in io): out = relu(h@W1^T+b1)@W2^T+b2
__global__ __launch_bounds__(256, 1) void mlp_kernel(
    const float* __restrict__ W1, const float* __restrict__ b1,
    const float* __restrict__ W2, const float* __restrict__ b2,
    float* __restrict__ io, int n) {
    int r = blockIdx.x * blockDim.x + threadIdx.x;
    if (r >= n) return;

    float h[EMB];
    const float4* qp = (const float4*)(io + (size_t)r * EMB);
    #pragma unroll
    for (int q = 0; q < EMB / 4; ++q) {
        float4 qv = qp[q];
        h[4 * q + 0] = qv.x;
        h[4 * q + 1] = qv.y;
        h[4 * q + 2] = qv.z;
        h[4 * q + 3] = qv.w;
    }

    float h1[EMB];
    #pragma unroll
    for (int j = 0; j < EMB; j += 4) {
        float s0 = b1[j + 0], s1 = b1[j + 1], s2 = b1[j + 2], s3 = b1[j + 3];
        #pragma unroll
        for (int k = 0; k < EMB; ++k) {
            float hk = h[k];
            s0 = fmaf(hk, W1[(j + 0) * EMB + k], s0);
            s1 = fmaf(hk, W1[(j + 1) * EMB + k], s1);
            s2 = fmaf(hk, W1[(j + 2) * EMB + k], s2);
            s3 = fmaf(hk, W1[(j + 3) * EMB + k], s3);
        }
        h1[j + 0] = fmaxf(s0, 0.f);
        h1[j + 1] = fmaxf(s1, 0.f);
        h1[j + 2] = fmaxf(s2, 0.f);
        h1[j + 3] = fmaxf(s3, 0.f);
    }

    float4* op = (float4*)(io + (size_t)r * EMB);
    #pragma unroll
    for (int j = 0; j < EMB; j += 4) {
        float s0 = b2[j + 0], s1 = b2[j + 1], s2 = b2[j + 2], s3 = b2[j + 3];
        #pragma unroll
        for (int k = 0; k < EMB; ++k) {
            float hk = h1[k];
            s0 = fmaf(hk, W2[(j + 0) * EMB + k], s0);
            s1 = fmaf(hk, W2[(j + 1) * EMB + k], s1);
            s2 = fmaf(hk, W2[(j + 2) * EMB + k], s2);
            s3 = fmaf(hk, W2[(j + 3) * EMB + k], s3);
        }
        op[j / 4] = make_float4(s0, s1, s2, s3);
    }
}

// ===================== mid-path kernels (row-level hist + scans) ==========

__global__ void hist_total_kernel(const int2* __restrict__ eidx,
                                  const float* __restrict__ w, int n_edges,
                                  int* __restrict__ counts,
                                  float* __restrict__ total) {
    int gid = blockIdx.x * blockDim.x + threadIdx.x;
    int stride = gridDim.x * blockDim.x;
    float s = 0.f;
    for (int e = gid; e < n_edges; e += stride) {
        s += w[e];
        atomicAdd(&counts[eidx[e].x], 1);
    }
    #pragma unroll
    for (int off = 32; off > 0; off >>= 1) s += __shfl_down(s, off, 64);
    if ((threadIdx.x & 63) == 0) atomicAdd(total, s);
}

__global__ __launch_bounds__(1024, 1) void scan1_kernel(
    const int* __restrict__ cnt, int* __restrict__ incl,
    int* __restrict__ bsums, int n) {
    __shared__ int s[1024];
    int t = threadIdx.x;
    int i = blockIdx.x * 1024 + t;
    int v = (i < n) ? cnt[i] : 0;
    s[t] = v;
    __syncthreads();
    for (int off = 1; off < 1024; off <<= 1) {
        int u = (t >= off) ? s[t - off] : 0;
        __syncthreads();
        s[t] += u;
        __syncthreads();
    }
    if (i < n) incl[i] = s[t];
    if (t == 1023) bsums[blockIdx.x] = s[t];
}

__global__ __launch_bounds__(256, 1) void scan2_kernel(int* __restrict__ bsums, int nb) {
    __shared__ int s[256];
    int t = threadIdx.x;
    int v = (t < nb) ? bsums[t] : 0;
    s[t] = v;
    __syncthreads();
    for (int off = 1; off < 256; off <<= 1) {
        int u = (t >= off) ? s[t - off] : 0;
        __syncthreads();
        s[t] += u;
        __syncthreads();
    }
    if (t < nb) bsums[t] = s[t] - v;
}

__global__ void scan3_kernel(const int* __restrict__ incl,
                             const int* __restrict__ base,
                             int* __restrict__ offs, int n) {
    int i = blockIdx.x * blockDim.x + threadIdx.x;
    if (i >= n) return;
    offs[i] = (i == 0) ? 0 : incl[i - 1] + base[(i - 1) >> 10];
}

__global__ void scatter_kernel(const int2* __restrict__ eidx,
                               const float* __restrict__ w, int n_edges,
                               int* __restrict__ offs,
                               int2* __restrict__ sorted) {
    int gid = blockIdx.x * blockDim.x + threadIdx.x;
    int stride = gridDim.x * blockDim.x;
    for (int e = gid; e < n_edges; e += stride) {
        int2 rc = eidx[e];
        float v = w[e];
        int pos = atomicAdd(&offs[rc.x], 1);
        sorted[pos] = make_int2(rc.y, __float_as_int(v));
    }
}

// ===================== fallback (atomic path) =====================

__global__ void sum_weights_kernel(const float* __restrict__ w, int n,
                                   float* __restrict__ total) {
    int gid = blockIdx.x * blockDim.x + threadIdx.x;
    int stride = gridDim.x * blockDim.x;
    float s = 0.f;
    for (int i = gid; i < n; i += stride) s += w[i];
    #pragma unroll
    for (int off = 32; off > 0; off >>= 1) s += __shfl_down(s, off, 64);
    if ((threadIdx.x & 63) == 0) atomicAdd(total, s);
}

__global__ void edge_scatter_kernel(const int* __restrict__ idx,
                                    const float* __restrict__ w,
                                    const float* __restrict__ left,
                                    const float* __restrict__ total,
                                    float* __restrict__ conv,
                                    long long n_threads) {
    long long gid = (long long)blockIdx.x * blockDim.x + threadIdx.x;
    if (gid >= n_threads) return;
    int e = (int)(gid >> 6);
    int d = (int)(gid & 63);
    float inv = 1.0f / fmaxf(total[0], 1.0f);
    int row = idx[2 * e];
    int col = idx[2 * e + 1];
    float v = w[e] * inv;
    float msg = left[(size_t)col * EMB + d] * v;
    atomicAdd(&conv[(size_t)row * EMB + d], msg);
}

__global__ __launch_bounds__(256, 1) void fused_mlp_kernel(
    const float* __restrict__ right, const float* __restrict__ c,
    const float* __restrict__ temp,
    const float* __restrict__ W1, const float* __restrict__ b1,
    const float* __restrict__ W2, const float* __restrict__ b2,
    float* __restrict__ io, int n) {
    int r = blockIdx.x * blockDim.x + threadIdx.x;
    if (r >= n) return;
    float t1 = temp[1];
    float cv = c[r];
    float h[EMB];
    const float4* rp = (const float4*)(right + (size_t)r * EMB);
    const float4* qp = (const float4*)(io + (size_t)r * EMB);
    #pragma unroll
    for (int q = 0; q < EMB / 4; ++q) {
        float4 rv = rp[q];
        float4 qv = qp[q];
        h[4 * q + 0] = rv.x + t1 * (cv - qv.x);
        h[4 * q + 1] = rv.y + t1 * (cv - qv.y);
        h[4 * q + 2] = rv.z + t1 * (cv - qv.z);
        h[4 * q + 3] = rv.w + t1 * (cv - qv.w);
    }
    float h1[EMB];
    #pragma unroll
    for (int j = 0; j < EMB; j += 4) {
        float s0 = b1[j], s1 = b1[j + 1], s2 = b1[j + 2], s3 = b1[j + 3];
        #pragma unroll
        for (int k = 0; k < EMB; ++k) {
            float hk = h[k];
            s0 = fmaf(hk, W1[(j + 0) * EMB + k], s0);
            s1 = fmaf(hk, W1[(j + 1) * EMB + k], s1);
            s2 = fmaf(hk, W1[(j + 2) * EMB + k], s2);
            s3 = fmaf(hk, W1[(j + 3) * EMB + k], s3);
        }
        h1[j] = fmaxf(s0, 0.f);
        h1[j + 1] = fmaxf(s1, 0.f);
        h1[j + 2] = fmaxf(s2, 0.f);
        h1[j + 3] = fmaxf(s3, 0.f);
    }
    float4* op = (float4*)(io + (size_t)r * EMB);
    #pragma unroll
    for (int j = 0; j < EMB; j += 4) {
        float s0 = b2[j], s1 = b2[j + 1], s2 = b2[j + 2], s3 = b2[j + 3];
        #pragma unroll
        for (int k = 0; k < EMB; ++k) {
            float hk = h1[k];
            s0 = fmaf(hk, W2[(j + 0) * EMB + k], s0);
            s1 = fmaf(hk, W2[(j + 1) * EMB + k], s1);
            s2 = fmaf(hk, W2[(j + 2) * EMB + k], s2);
            s3 = fmaf(hk, W2[(j + 3) * EMB + k], s3);
        }
        op[j / 4] = make_float4(s0, s1, s2, s3);
    }
}

// ===================== launch =====================

extern "C" void kernel_launch(void* const* d_in, const int* in_sizes, int n_in,
                              void* d_out, int out_size, void* d_ws, size_t ws_size,
                              hipStream_t stream) {
    const float* left   = (const float*)d_in[0];
    const int*   eidx   = (const int*)d_in[2];
    const float* ew     = (const float*)d_in[3];
    const float* right  = (const float*)d_in[4];
    const float* c      = (const float*)d_in[5];
    const float* temp   = (const float*)d_in[7];
    const float* W1     = (const float*)d_in[8];
    const float* b1     = (const float*)d_in[9];
    const float* W2     = (const float*)d_in[10];
    const float* b2     = (const float*)d_in[11];

    const int n_edges = in_sizes[3];
    const int n_right = in_sizes[4] / EMB;
    const int n_left  = in_sizes[0] / EMB;
    float* out = (float*)d_out;

    const int nb = (n_right + BROWS - 1) >> BSHIFT;
    const int nblocks_scan = (n_right + 1023) / 1024;

    auto align256 = [](size_t x) { return (x + 255) & ~(size_t)255; };

    // ws layout (full path): total | bbase(nb+1) | bcursor(nb) | offs(n_right)
    //                        | bsorted | sorted2 | left16
    size_t off_bbase  = 64;
    size_t off_bcur   = align256(off_bbase + (size_t)(nb + 1) * 4);
    size_t off_offs   = align256(off_bcur + (size_t)nb * 4);
    size_t off_incl   = align256(off_offs + (size_t)n_right * 4);   // mid only
    size_t off_bsum   = align256(off_incl + (size_t)n_right * 4);   // mid only
    size_t off_bsorted = align256(off_bsum + 1024);
    size_t off_sorted2 = align256(off_bsorted + (size_t)n_edges * 8);
    size_t off_left16_full = align256(off_sorted2 + (size_t)n_edges * 8);
    size_t req_full = off_left16_full + (size_t)n_left * EMB * 2;
    size_t off_left16_mid = off_sorted2;
    size_t req_mid = off_left16_mid + (size_t)n_left * EMB * 2;

    bool common_ok = (nb <= 256) && (nblocks_scan <= 256) &&
                     (n_left <= (1 << COLBITS)) && (BROWS * nb >= n_right);

    if (common_ok && ws_size >= req_full) {
        // ---------- full path: bucket hist + partition + local rowsort ----
        char* ws = (char*)d_ws;
        float* total = (float*)ws;
        int* bbase = (int*)(ws + off_bbase);
        int* bcur = (int*)(ws + off_bcur);
        int* offs = (int*)(ws + off_offs);
        int2* bsorted = (int2*)(ws + off_bsorted);
        int2* sorted2 = (int2*)(ws + off_sorted2);
        unsigned short* left16 = (unsigned short*)(ws + off_left16_full);

        // zero total + bucket counts only (tiny)
        hipMemsetAsync(ws, 0, off_bbase + (size_t)(nb + 1) * 4, stream);

        int n2 = n_left * EMB / 2;
        convert_left_kernel<<<(n2 + 255) / 256, 256, 0, stream>>>(
            left, (unsigned*)left16, n2);
        bucket_hist_kernel<<<512, 256, 0, stream>>>((const int2*)eidx, ew,
                                                    n_edges, nb, bbase, total);
        bucket_scan_kernel<<<1, 256, 0, stream>>>(bbase, bcur, nb, n_edges);
        {
            int nchunks = (n_edges + CHUNK - 1) / CHUNK;
            partition_kernel<<<nchunks, 256, 0, stream>>>(
                (const int2*)eidx, ew, n_edges, nb, bcur, bsorted);
        }
        local_rowsort_kernel<<<nb, 256, 0, stream>>>(bsorted, bbase, offs,
                                                     sorted2, n_right);
        {
            long long n_threads = (long long)n_right * EMB;
            int blocks = (int)((n_threads + 255) / 256);
            seg_gather_bf16_kernel<<<blocks, 256, 0, stream>>>(
                sorted2, offs, left16, right, c, temp, total, out, n_right,
                n_edges, 0);
        }
        mlp_kernel<<<(n_right + 255) / 256, 256, 0, stream>>>(W1, b1, W2, b2,
                                                              out, n_right);
    } else if (common_ok && ws_size >= req_mid) {
        // ---------- mid path: round-3 proven structure ----------
        char* ws = (char*)d_ws;
        float* total = (float*)ws;
        int* offs = (int*)(ws + off_offs);
        int* incl = (int*)(ws + off_incl);
        int* bsum = (int*)(ws + off_bsum);
        int2* sorted = (int2*)(ws + off_bsorted);
        unsigned short* left16 = (unsigned short*)(ws + off_left16_mid);

        hipMemsetAsync(ws, 0, off_offs + (size_t)n_right * 4, stream);

        int n2 = n_left * EMB / 2;
        convert_left_kernel<<<(n2 + 255) / 256, 256, 0, stream>>>(
            left, (unsigned*)left16, n2);
        hist_total_kernel<<<2048, 256, 0, stream>>>((const int2*)eidx, ew,
                                                    n_edges, offs, total);
        scan1_kernel<<<nblocks_scan, 1024, 0, stream>>>(offs, incl, bsum, n_right);
        scan2_kernel<<<1, 256, 0, stream>>>(bsum, nblocks_scan);
        scan3_kernel<<<(n_right + 255) / 256, 256, 0, stream>>>(incl, bsum, offs,
                                                                n_right);
        scatter_kernel<<<2048, 256, 0, stream>>>((const int2*)eidx, ew, n_edges,
                                                 offs, sorted);
        {
            long long n_threads = (long long)n_right * EMB;
            int blocks = (int)((n_threads + 255) / 256);
            seg_gather_bf16_kernel<<<blocks, 256, 0, stream>>>(
                sorted, offs, left16, right, c, temp, total, out, n_right,
                n_edges, 1);
        }
        mlp_kernel<<<(n_right + 255) / 256, 256, 0, stream>>>(W1, b1, W2, b2,
                                                              out, n_right);
    } else {
        // ---------- fallback: atomic path ----------
        float* total = (float*)d_ws;
        hipMemsetAsync(d_out, 0, (size_t)out_size * sizeof(float), stream);
        hipMemsetAsync(d_ws, 0, sizeof(float), stream);
        sum_weights_kernel<<<2048, 256, 0, stream>>>(ew, n_edges, total);
        long long n_threads = (long long)n_edges * EMB;
        long long blocks = (n_threads + 255) / 256;
        edge_scatter_kernel<<<(int)blocks, 256, 0, stream>>>(
            eidx, ew, left, total, out, n_threads);
        int mblocks = (n_right + 255) / 256;
        fused_mlp_kernel<<<mblocks, 256, 0, stream>>>(right, c, temp, W1, b1, W2,
                                                      b2, out, n_right);
    }
}

// Round 7
// 324.841 us; speedup vs baseline: 4.7136x; 1.0244x over previous
//
#include <hip/hip_runtime.h>

#define EMB 64
#define BROWS 512            // rows per bucket
#define BSHIFT 9             // log2(BROWS)
#define CHUNK 4096           // edges per partition block
#define COLBITS 23
#define COLMASK ((1u << COLBITS) - 1u)

// bf16 helpers (manual RNE pack/unpack)
__device__ __forceinline__ unsigned short f2bf(float f) {
    unsigned u = __float_as_uint(f);
    u = u + 0x7FFFu + ((u >> 16) & 1u);
    return (unsigned short)(u >> 16);
}

// K0: convert left (f32) -> left16 (bf16), 2 elems/thread
__global__ void convert_left_kernel(const float* __restrict__ left,
                                    unsigned* __restrict__ left16, int n2) {
    int i = blockIdx.x * blockDim.x + threadIdx.x;
    if (i >= n2) return;
    float2 v = ((const float2*)left)[i];
    left16[i] = (unsigned)f2bf(v.x) | ((unsigned)f2bf(v.y) << 16);
}

// K1: LDS-aggregated bucket histogram (nb<=256 bins) + total = sum(w)
__global__ __launch_bounds__(256) void bucket_hist_kernel(
    const int2* __restrict__ eidx, const float* __restrict__ w, int n_edges,
    int nb, int* __restrict__ bcount, float* __restrict__ total) {
    __shared__ int lh[256];
    int t = threadIdx.x;
    lh[t] = 0;
    __syncthreads();
    int gid = blockIdx.x * 256 + t;
    int stride = gridDim.x * 256;
    float s = 0.f;
    for (int e = gid; e < n_edges; e += stride) {
        s += w[e];
        atomicAdd(&lh[eidx[e].x >> BSHIFT], 1);
    }
    #pragma unroll
    for (int off = 32; off > 0; off >>= 1) s += __shfl_down(s, off, 64);
    if ((t & 63) == 0) atomicAdd(total, s);
    __syncthreads();
    if (t < nb && lh[t]) atomicAdd(&bcount[t], lh[t]);
}

// K2: single-block exclusive scan of bucket counts (nb <= 256), in place.
__global__ __launch_bounds__(256, 1) void bucket_scan_kernel(
    int* __restrict__ bbase, int* __restrict__ bcursor, int nb, int n_edges) {
    __shared__ int ssc[256];
    int t = threadIdx.x;
    int v = (t < nb) ? bbase[t] : 0;
    ssc[t] = v;
    __syncthreads();
    for (int off = 1; off < 256; off <<= 1) {
        int u = (t >= off) ? ssc[t - off] : 0;
        __syncthreads();
        ssc[t] += u;
        __syncthreads();
    }
    int excl = ssc[t] - v;
    if (t < nb) { bbase[t] = excl; bcursor[t] = excl; }
    if (t == 0) bbase[nb] = n_edges;
}

// K3: partition edges into buckets with LDS staging for coalesced writes.
__global__ __launch_bounds__(256) void partition_kernel(
    const int2* __restrict__ eidx, const float* __restrict__ w, int n_edges,
    int nb, int* __restrict__ bcursor, int2* __restrict__ bsorted) {
    __shared__ int lh[256];
    __shared__ int lo[256];
    __shared__ int go[256];
    __shared__ int lcur[256];
    __shared__ int2 stage[CHUNK];
    __shared__ int dstg[CHUNK];
    int t = threadIdx.x;
    int base = blockIdx.x * CHUNK;
    int cnt = min(CHUNK, n_edges - base);

    lh[t] = 0;
    __syncthreads();
    #pragma unroll
    for (int k = 0; k < CHUNK / 256; ++k) {
        int e = base + t + k * 256;
        if (e < n_edges) atomicAdd(&lh[eidx[e].x >> BSHIFT], 1);
    }
    __syncthreads();
    int v = lh[t];
    lo[t] = v;
    __syncthreads();
    for (int off = 1; off < 256; off <<= 1) {
        int u = (t >= off) ? lo[t - off] : 0;
        __syncthreads();
        lo[t] += u;
        __syncthreads();
    }
    int excl = lo[t] - v;
    go[t] = (v > 0) ? atomicAdd(&bcursor[t], v) : 0;
    __syncthreads();
    lo[t] = excl;
    lcur[t] = excl;
    __syncthreads();

    #pragma unroll
    for (int k = 0; k < CHUNK / 256; ++k) {
        int e = base + t + k * 256;
        if (e < n_edges) {
            int2 rc = eidx[e];
            float wv = w[e];
            int b = rc.x >> BSHIFT;
            unsigned rl = (unsigned)(rc.x & (BROWS - 1));
            int p = atomicAdd(&lcur[b], 1);
            stage[p] = make_int2((int)((rl << COLBITS) | (unsigned)rc.y),
                                 __float_as_int(wv));
            dstg[p] = go[b] + (p - lo[b]);
        }
    }
    __syncthreads();
    #pragma unroll
    for (int k = 0; k < CHUNK / 256; ++k) {
        int s = t + k * 256;
        if (s < cnt) bsorted[dstg[s]] = stage[s];
    }
}

// K3b: one block per bucket: per-row offsets in LDS + L2-local row scatter.
__global__ __launch_bounds__(256) void local_rowsort_kernel(
    const int2* __restrict__ bsorted, const int* __restrict__ bbase,
    int* __restrict__ offs, int2* __restrict__ sorted2, int n_right) {
    __shared__ int lhist[BROWS];
    __shared__ int lcur[BROWS];
    __shared__ int ps[256];
    int b = blockIdx.x;
    int t = threadIdx.x;
    int start = bbase[b];
    int end = bbase[b + 1];
    int row0 = b << BSHIFT;
    int nrows = min(BROWS, n_right - row0);

    lhist[2 * t] = 0;
    lhist[2 * t + 1] = 0;
    __syncthreads();
    for (int e = start + t; e < end; e += 256)
        atomicAdd(&lhist[((unsigned)bsorted[e].x) >> COLBITS], 1);
    __syncthreads();

    int v0 = lhist[2 * t];
    int v1 = lhist[2 * t + 1];
    int pv = v0 + v1;
    ps[t] = pv;
    __syncthreads();
    for (int off = 1; off < 256; off <<= 1) {
        int u = (t >= off) ? ps[t - off] : 0;
        __syncthreads();
        ps[t] += u;
        __syncthreads();
    }
    int epair = ps[t] - pv;
    lcur[2 * t] = epair;
    lcur[2 * t + 1] = epair + v0;
    if (2 * t < nrows)     offs[row0 + 2 * t]     = start + epair;
    if (2 * t + 1 < nrows) offs[row0 + 2 * t + 1] = start + epair + v0;
    __syncthreads();

    int e = start + t;
    for (; e + 3 * 256 < end; e += 4 * 256) {
        int2 e0 = bsorted[e + 0 * 256];
        int2 e1 = bsorted[e + 1 * 256];
        int2 e2 = bsorted[e + 2 * 256];
        int2 e3 = bsorted[e + 3 * 256];
        int p0 = atomicAdd(&lcur[((unsigned)e0.x) >> COLBITS], 1);
        int p1 = atomicAdd(&lcur[((unsigned)e1.x) >> COLBITS], 1);
        int p2 = atomicAdd(&lcur[((unsigned)e2.x) >> COLBITS], 1);
        int p3 = atomicAdd(&lcur[((unsigned)e3.x) >> COLBITS], 1);
        sorted2[start + p0] = e0;
        sorted2[start + p1] = e1;
        sorted2[start + p2] = e2;
        sorted2[start + p3] = e3;
    }
    for (; e < end; e += 256) {
        int2 e0 = bsorted[e];
        int p0 = atomicAdd(&lcur[((unsigned)e0.x) >> COLBITS], 1);
        sorted2[start + p0] = e0;
    }
}

// K4: one wave per row, 4 edges per iteration.
// lane = (sub<<4) | d4 : sub = edge-in-group, d4 = dim quad (4 bf16 dims).
// One gather instruction covers 4 edges (4 x 128B). After the loop, reduce
// across sub-groups via shfl_xor(16/32); lanes 0-15 write the row.
__global__ void seg_gather_bf16_kernel(const int2* __restrict__ sorted,
                                       const int* __restrict__ offs,
                                       const uint2* __restrict__ left16q,
                                       const float* __restrict__ right,
                                       const float* __restrict__ c,
                                       const float* __restrict__ temp,
                                       const float* __restrict__ total,
                                       float* __restrict__ hout, int n_right,
                                       int n_edges, int offs_are_ends) {
    int gid = blockIdx.x * blockDim.x + threadIdx.x;
    int wid = gid >> 6;
    int lane = gid & 63;
    if (wid >= n_right) return;
    int start, end;
    if (offs_are_ends) {
        end = offs[wid];
        start = (wid == 0) ? 0 : offs[wid - 1];
    } else {
        start = offs[wid];
        end = (wid + 1 < n_right) ? offs[wid + 1] : n_edges;
    }

    int sub = lane >> 4;       // edge within group of 4
    int d4  = lane & 15;       // dim quad

    float a0 = 0.f, a1 = 0.f, a2 = 0.f, a3 = 0.f;
    int e0 = start;
    for (; e0 + 4 <= end; e0 += 4) {
        int2 sv = sorted[e0 + sub];
        unsigned col = (unsigned)sv.x & COLMASK;
        uint2 pk = left16q[(size_t)col * 16 + d4];
        float wv = __int_as_float(sv.y);
        a0 = fmaf(wv, __uint_as_float(pk.x << 16), a0);
        a1 = fmaf(wv, __uint_as_float(pk.x & 0xffff0000u), a1);
        a2 = fmaf(wv, __uint_as_float(pk.y << 16), a2);
        a3 = fmaf(wv, __uint_as_float(pk.y & 0xffff0000u), a3);
    }
    if (e0 < end) {            // tail: 1..3 edges
        int e = e0 + sub;
        int2 sv = sorted[(e < end) ? e : (end - 1)];
        float wv = (e < end) ? __int_as_float(sv.y) : 0.f;
        unsigned col = (unsigned)sv.x & COLMASK;
        uint2 pk = left16q[(size_t)col * 16 + d4];
        a0 = fmaf(wv, __uint_as_float(pk.x << 16), a0);
        a1 = fmaf(wv, __uint_as_float(pk.x & 0xffff0000u), a1);
        a2 = fmaf(wv, __uint_as_float(pk.y << 16), a2);
        a3 = fmaf(wv, __uint_as_float(pk.y & 0xffff0000u), a3);
    }

    // reduce over the 4 edge-subgroups (lane bits 4 and 5)
    a0 += __shfl_xor(a0, 16, 64); a0 += __shfl_xor(a0, 32, 64);
    a1 += __shfl_xor(a1, 16, 64); a1 += __shfl_xor(a1, 32, 64);
    a2 += __shfl_xor(a2, 16, 64); a2 += __shfl_xor(a2, 32, 64);
    a3 += __shfl_xor(a3, 16, 64); a3 += __shfl_xor(a3, 32, 64);

    if (lane < 16) {
        float inv = 1.0f / fmaxf(total[0], 1.0f);
        float t1 = temp[1];
        float cv = c[wid];
        float4 rv = ((const float4*)(right + (size_t)wid * EMB))[lane];
        float4 hv;
        hv.x = rv.x + t1 * (cv - a0 * inv);
        hv.y = rv.y + t1 * (cv - a1 * inv);
        hv.z = rv.z + t1 * (cv - a2 * inv);
        hv.w = rv.w + t1 * (cv - a3 * inv);
        ((float4*)(hout + (size_t)wid * EMB))[lane] = hv;
    }
}

// K5: MLP on h (in place in io): out = relu(h@W1^T+b1)@W2^T+b2
__global__ __launch_bounds__(256, 1) void mlp_kernel(
    const float* __restrict__ W1, const float* __restrict__ b1,
    const float* __restrict__ W2, const float* __restrict__ b2,
    float* __restrict__ io, int n) {
    int r = blockIdx.x * blockDim.x + threadIdx.x;
    if (r >= n) return;

    float h[EMB];
    const float4* qp = (const float4*)(io + (size_t)r * EMB);
    #pragma unroll
    for (int q = 0; q < EMB / 4; ++q) {
        float4 qv = qp[q];
        h[4 * q + 0] = qv.x;
        h[4 * q + 1] = qv.y;
        h[4 * q + 2] = qv.z;
        h[4 * q + 3] = qv.w;
    }

    float h1[EMB];
    #pragma unroll
    for (int j = 0; j < EMB; j += 4) {
        float s0 = b1[j + 0], s1 = b1[j + 1], s2 = b1[j + 2], s3 = b1[j + 3];
        #pragma unroll
        for (int k = 0; k < EMB; ++k) {
            float hk = h[k];
            s0 = fmaf(hk, W1[(j + 0) * EMB + k], s0);
            s1 = fmaf(hk, W1[(j + 1) * EMB + k], s1);
            s2 = fmaf(hk, W1[(j + 2) * EMB + k], s2);
            s3 = fmaf(hk, W1[(j + 3) * EMB + k], s3);
        }
        h1[j + 0] = fmaxf(s0, 0.f);
        h1[j + 1] = fmaxf(s1, 0.f);
        h1[j + 2] = fmaxf(s2, 0.f);
        h1[j + 3] = fmaxf(s3, 0.f);
    }

    float4* op = (float4*)(io + (size_t)r * EMB);
    #pragma unroll
    for (int j = 0; j < EMB; j += 4) {
        float s0 = b2[j + 0], s1 = b2[j + 1], s2 = b2[j + 2], s3 = b2[j + 3];
        #pragma unroll
        for (int k = 0; k < EMB; ++k) {
            float hk = h1[k];
            s0 = fmaf(hk, W2[(j + 0) * EMB + k], s0);
            s1 = fmaf(hk, W2[(j + 1) * EMB + k], s1);
            s2 = fmaf(hk, W2[(j + 2) * EMB + k], s2);
            s3 = fmaf(hk, W2[(j + 3) * EMB + k], s3);
        }
        op[j / 4] = make_float4(s0, s1, s2, s3);
    }
}

// ===================== mid-path kernels (row-level hist + scans) ==========

__global__ void hist_total_kernel(const int2* __restrict__ eidx,
                                  const float* __restrict__ w, int n_edges,
                                  int* __restrict__ counts,
                                  float* __restrict__ total) {
    int gid = blockIdx.x * blockDim.x + threadIdx.x;
    int stride = gridDim.x * blockDim.x;
    float s = 0.f;
    for (int e = gid; e < n_edges; e += stride) {
        s += w[e];
        atomicAdd(&counts[eidx[e].x], 1);
    }
    #pragma unroll
    for (int off = 32; off > 0; off >>= 1) s += __shfl_down(s, off, 64);
    if ((threadIdx.x & 63) == 0) atomicAdd(total, s);
}

__global__ __launch_bounds__(1024, 1) void scan1_kernel(
    const int* __restrict__ cnt, int* __restrict__ incl,
    int* __restrict__ bsums, int n) {
    __shared__ int s[1024];
    int t = threadIdx.x;
    int i = blockIdx.x * 1024 + t;
    int v = (i < n) ? cnt[i] : 0;
    s[t] = v;
    __syncthreads();
    for (int off = 1; off < 1024; off <<= 1) {
        int u = (t >= off) ? s[t - off] : 0;
        __syncthreads();
        s[t] += u;
        __syncthreads();
    }
    if (i < n) incl[i] = s[t];
    if (t == 1023) bsums[blockIdx.x] = s[t];
}

__global__ __launch_bounds__(256, 1) void scan2_kernel(int* __restrict__ bsums, int nb) {
    __shared__ int s[256];
    int t = threadIdx.x;
    int v = (t < nb) ? bsums[t] : 0;
    s[t] = v;
    __syncthreads();
    for (int off = 1; off < 256; off <<= 1) {
        int u = (t >= off) ? s[t - off] : 0;
        __syncthreads();
        s[t] += u;
        __syncthreads();
    }
    if (t < nb) bsums[t] = s[t] - v;
}

__global__ void scan3_kernel(const int* __restrict__ incl,
                             const int* __restrict__ base,
                             int* __restrict__ offs, int n) {
    int i = blockIdx.x * blockDim.x + threadIdx.x;
    if (i >= n) return;
    offs[i] = (i == 0) ? 0 : incl[i - 1] + base[(i - 1) >> 10];
}

__global__ void scatter_kernel(const int2* __restrict__ eidx,
                               const float* __restrict__ w, int n_edges,
                               int* __restrict__ offs,
                               int2* __restrict__ sorted) {
    int gid = blockIdx.x * blockDim.x + threadIdx.x;
    int stride = gridDim.x * blockDim.x;
    for (int e = gid; e < n_edges; e += stride) {
        int2 rc = eidx[e];
        float v = w[e];
        int pos = atomicAdd(&offs[rc.x], 1);
        sorted[pos] = make_int2(rc.y, __float_as_int(v));
    }
}

// ===================== fallback (atomic path) =====================

__global__ void sum_weights_kernel(const float* __restrict__ w, int n,
                                   float* __restrict__ total) {
    int gid = blockIdx.x * blockDim.x + threadIdx.x;
    int stride = gridDim.x * blockDim.x;
    float s = 0.f;
    for (int i = gid; i < n; i += stride) s += w[i];
    #pragma unroll
    for (int off = 32; off > 0; off >>= 1) s += __shfl_down(s, off, 64);
    if ((threadIdx.x & 63) == 0) atomicAdd(total, s);
}

__global__ void edge_scatter_kernel(const int* __restrict__ idx,
                                    const float* __restrict__ w,
                                    const float* __restrict__ left,
                                    const float* __restrict__ total,
                                    float* __restrict__ conv,
                                    long long n_threads) {
    long long gid = (long long)blockIdx.x * blockDim.x + threadIdx.x;
    if (gid >= n_threads) return;
    int e = (int)(gid >> 6);
    int d = (int)(gid & 63);
    float inv = 1.0f / fmaxf(total[0], 1.0f);
    int row = idx[2 * e];
    int col = idx[2 * e + 1];
    float v = w[e] * inv;
    float msg = left[(size_t)col * EMB + d] * v;
    atomicAdd(&conv[(size_t)row * EMB + d], msg);
}

__global__ __launch_bounds__(256, 1) void fused_mlp_kernel(
    const float* __restrict__ right, const float* __restrict__ c,
    const float* __restrict__ temp,
    const float* __restrict__ W1, const float* __restrict__ b1,
    const float* __restrict__ W2, const float* __restrict__ b2,
    float* __restrict__ io, int n) {
    int r = blockIdx.x * blockDim.x + threadIdx.x;
    if (r >= n) return;
    float t1 = temp[1];
    float cv = c[r];
    float h[EMB];
    const float4* rp = (const float4*)(right + (size_t)r * EMB);
    const float4* qp = (const float4*)(io + (size_t)r * EMB);
    #pragma unroll
    for (int q = 0; q < EMB / 4; ++q) {
        float4 rv = rp[q];
        float4 qv = qp[q];
        h[4 * q + 0] = rv.x + t1 * (cv - qv.x);
        h[4 * q + 1] = rv.y + t1 * (cv - qv.y);
        h[4 * q + 2] = rv.z + t1 * (cv - qv.z);
        h[4 * q + 3] = rv.w + t1 * (cv - qv.w);
    }
    float h1[EMB];
    #pragma unroll
    for (int j = 0; j < EMB; j += 4) {
        float s0 = b1[j], s1 = b1[j + 1], s2 = b1[j + 2], s3 = b1[j + 3];
        #pragma unroll
        for (int k = 0; k < EMB; ++k) {
            float hk = h[k];
            s0 = fmaf(hk, W1[(j + 0) * EMB + k], s0);
            s1 = fmaf(hk, W1[(j + 1) * EMB + k], s1);
            s2 = fmaf(hk, W1[(j + 2) * EMB + k], s2);
            s3 = fmaf(hk, W1[(j + 3) * EMB + k], s3);
        }
        h1[j] = fmaxf(s0, 0.f);
        h1[j + 1] = fmaxf(s1, 0.f);
        h1[j + 2] = fmaxf(s2, 0.f);
        h1[j + 3] = fmaxf(s3, 0.f);
    }
    float4* op = (float4*)(io + (size_t)r * EMB);
    #pragma unroll
    for (int j = 0; j < EMB; j += 4) {
        float s0 = b2[j], s1 = b2[j + 1], s2 = b2[j + 2], s3 = b2[j + 3];
        #pragma unroll
        for (int k = 0; k < EMB; ++k) {
            float hk = h1[k];
            s0 = fmaf(hk, W2[(j + 0) * EMB + k], s0);
            s1 = fmaf(hk, W2[(j + 1) * EMB + k], s1);
            s2 = fmaf(hk, W2[(j + 2) * EMB + k], s2);
            s3 = fmaf(hk, W2[(j + 3) * EMB + k], s3);
        }
        op[j / 4] = make_float4(s0, s1, s2, s3);
    }
}

// ===================== launch =====================

extern "C" void kernel_launch(void* const* d_in, const int* in_sizes, int n_in,
                              void* d_out, int out_size, void* d_ws, size_t ws_size,
                              hipStream_t stream) {
    const float* left   = (const float*)d_in[0];
    const int*   eidx   = (const int*)d_in[2];
    const float* ew     = (const float*)d_in[3];
    const float* right  = (const float*)d_in[4];
    const float* c      = (const float*)d_in[5];
    const float* temp   = (const float*)d_in[7];
    const float* W1     = (const float*)d_in[8];
    const float* b1     = (const float*)d_in[9];
    const float* W2     = (const float*)d_in[10];
    const float* b2     = (const float*)d_in[11];

    const int n_edges = in_sizes[3];
    const int n_right = in_sizes[4] / EMB;
    const int n_left  = in_sizes[0] / EMB;
    float* out = (float*)d_out;

    const int nb = (n_right + BROWS - 1) >> BSHIFT;
    const int nblocks_scan = (n_right + 1023) / 1024;

    auto align256 = [](size_t x) { return (x + 255) & ~(size_t)255; };

    size_t off_bbase  = 64;
    size_t off_bcur   = align256(off_bbase + (size_t)(nb + 1) * 4);
    size_t off_offs   = align256(off_bcur + (size_t)nb * 4);
    size_t off_incl   = align256(off_offs + (size_t)n_right * 4);   // mid only
    size_t off_bsum   = align256(off_incl + (size_t)n_right * 4);   // mid only
    size_t off_bsorted = align256(off_bsum + 1024);
    size_t off_sorted2 = align256(off_bsorted + (size_t)n_edges * 8);
    size_t off_left16_full = align256(off_sorted2 + (size_t)n_edges * 8);
    size_t req_full = off_left16_full + (size_t)n_left * EMB * 2;
    size_t off_left16_mid = off_sorted2;
    size_t req_mid = off_left16_mid + (size_t)n_left * EMB * 2;

    bool common_ok = (nb <= 256) && (nblocks_scan <= 256) &&
                     (n_left <= (1 << COLBITS)) && (BROWS * nb >= n_right);

    if (common_ok && ws_size >= req_full) {
        // ---------- full path: bucket hist + partition + local rowsort ----
        char* ws = (char*)d_ws;
        float* total = (float*)ws;
        int* bbase = (int*)(ws + off_bbase);
        int* bcur = (int*)(ws + off_bcur);
        int* offs = (int*)(ws + off_offs);
        int2* bsorted = (int2*)(ws + off_bsorted);
        int2* sorted2 = (int2*)(ws + off_sorted2);
        unsigned short* left16 = (unsigned short*)(ws + off_left16_full);

        hipMemsetAsync(ws, 0, off_bbase + (size_t)(nb + 1) * 4, stream);

        int n2 = n_left * EMB / 2;
        convert_left_kernel<<<(n2 + 255) / 256, 256, 0, stream>>>(
            left, (unsigned*)left16, n2);
        bucket_hist_kernel<<<512, 256, 0, stream>>>((const int2*)eidx, ew,
                                                    n_edges, nb, bbase, total);
        bucket_scan_kernel<<<1, 256, 0, stream>>>(bbase, bcur, nb, n_edges);
        {
            int nchunks = (n_edges + CHUNK - 1) / CHUNK;
            partition_kernel<<<nchunks, 256, 0, stream>>>(
                (const int2*)eidx, ew, n_edges, nb, bcur, bsorted);
        }
        local_rowsort_kernel<<<nb, 256, 0, stream>>>(bsorted, bbase, offs,
                                                     sorted2, n_right);
        {
            long long n_threads = (long long)n_right * EMB;
            int blocks = (int)((n_threads + 255) / 256);
            seg_gather_bf16_kernel<<<blocks, 256, 0, stream>>>(
                sorted2, offs, (const uint2*)left16, right, c, temp, total,
                out, n_right, n_edges, 0);
        }
        mlp_kernel<<<(n_right + 255) / 256, 256, 0, stream>>>(W1, b1, W2, b2,
                                                              out, n_right);
    } else if (common_ok && ws_size >= req_mid) {
        // ---------- mid path: round-3 proven structure ----------
        char* ws = (char*)d_ws;
        float* total = (float*)ws;
        int* offs = (int*)(ws + off_offs);
        int* incl = (int*)(ws + off_incl);
        int* bsum = (int*)(ws + off_bsum);
        int2* sorted = (int2*)(ws + off_bsorted);
        unsigned short* left16 = (unsigned short*)(ws + off_left16_mid);

        hipMemsetAsync(ws, 0, off_offs + (size_t)n_right * 4, stream);

        int n2 = n_left * EMB / 2;
        convert_left_kernel<<<(n2 + 255) / 256, 256, 0, stream>>>(
            left, (unsigned*)left16, n2);
        hist_total_kernel<<<2048, 256, 0, stream>>>((const int2*)eidx, ew,
                                                    n_edges, offs, total);
        scan1_kernel<<<nblocks_scan, 1024, 0, stream>>>(offs, incl, bsum, n_right);
        scan2_kernel<<<1, 256, 0, stream>>>(bsum, nblocks_scan);
        scan3_kernel<<<(n_right + 255) / 256, 256, 0, stream>>>(incl, bsum, offs,
                                                                n_right);
        scatter_kernel<<<2048, 256, 0, stream>>>((const int2*)eidx, ew, n_edges,
                                                 offs, sorted);
        {
            long long n_threads = (long long)n_right * EMB;
            int blocks = (int)((n_threads + 255) / 256);
            seg_gather_bf16_kernel<<<blocks, 256, 0, stream>>>(
                sorted, offs, (const uint2*)left16, right, c, temp, total,
                out, n_right, n_edges, 1);
        }
        mlp_kernel<<<(n_right + 255) / 256, 256, 0, stream>>>(W1, b1, W2, b2,
                                                              out, n_right);
    } else {
        // ---------- fallback: atomic path ----------
        float* total = (float*)d_ws;
        hipMemsetAsync(d_out, 0, (size_t)out_size * sizeof(float), stream);
        hipMemsetAsync(d_ws, 0, sizeof(float), stream);
        sum_weights_kernel<<<2048, 256, 0, stream>>>(ew, n_edges, total);
        long long n_threads = (long long)n_edges * EMB;
        long long blocks = (n_threads + 255) / 256;
        edge_scatter_kernel<<<(int)blocks, 256, 0, stream>>>(
            eidx, ew, left, total, out, n_threads);
        int mblocks = (n_right + 255) / 256;
        fused_mlp_kernel<<<mblocks, 256, 0, stream>>>(right, c, temp, W1, b1, W2,
                                                      b2, out, n_right);
    }
}

// Round 8
// 279.428 us; speedup vs baseline: 5.4797x; 1.1625x over previous
//
#include <hip/hip_runtime.h>

#define EMB 64
#define BROWS 512            // rows per bucket
#define BSHIFT 9             // log2(BROWS)
#define CHUNK 4096           // edges per partition block
#define COLBITS 23
#define COLMASK ((1u << COLBITS) - 1u)

// bf16 pack (RNE)
__device__ __forceinline__ unsigned short f2bf(float f) {
    unsigned u = __float_as_uint(f);
    u = u + 0x7FFFu + ((u >> 16) & 1u);
    return (unsigned short)(u >> 16);
}

// K0: convert left (f32) -> left16 (bf16), 2 elems/thread
__global__ void convert_left_kernel(const float* __restrict__ left,
                                    unsigned* __restrict__ left16, int n2) {
    int i = blockIdx.x * blockDim.x + threadIdx.x;
    if (i >= n2) return;
    float2 v = ((const float2*)left)[i];
    left16[i] = (unsigned)f2bf(v.x) | ((unsigned)f2bf(v.y) << 16);
}

// K1: bcur[b] = b*slot
__global__ void init_bcur_kernel(int* __restrict__ bcur, int nb, int slot) {
    int t = threadIdx.x;
    if (t < nb) bcur[t] = t * slot;
}

// K2: partition edges into slack-slotted buckets (LDS-staged coalesced writes)
// and compute total = sum(w). bsorted[i] = ((row_local<<COLBITS)|col, bits(w)).
__global__ __launch_bounds__(256) void partition_kernel(
    const int2* __restrict__ eidx, const float* __restrict__ w, int n_edges,
    int* __restrict__ bcursor, int2* __restrict__ bsorted,
    float* __restrict__ total) {
    __shared__ int lh[256];
    __shared__ int lo[256];
    __shared__ int go[256];
    __shared__ int lcur[256];
    __shared__ int2 stage[CHUNK];
    __shared__ int dstg[CHUNK];
    int t = threadIdx.x;
    int base = blockIdx.x * CHUNK;
    int cnt = min(CHUNK, n_edges - base);

    lh[t] = 0;
    __syncthreads();
    #pragma unroll
    for (int k = 0; k < CHUNK / 256; ++k) {
        int e = base + t + k * 256;
        if (e < n_edges) atomicAdd(&lh[eidx[e].x >> BSHIFT], 1);
    }
    __syncthreads();
    int v = lh[t];
    lo[t] = v;
    __syncthreads();
    for (int off = 1; off < 256; off <<= 1) {
        int u = (t >= off) ? lo[t - off] : 0;
        __syncthreads();
        lo[t] += u;
        __syncthreads();
    }
    int excl = lo[t] - v;
    go[t] = (v > 0) ? atomicAdd(&bcursor[t], v) : 0;
    __syncthreads();
    lo[t] = excl;
    lcur[t] = excl;
    __syncthreads();

    float s = 0.f;
    #pragma unroll
    for (int k = 0; k < CHUNK / 256; ++k) {
        int e = base + t + k * 256;
        if (e < n_edges) {
            int2 rc = eidx[e];
            float wv = w[e];
            s += wv;
            int b = rc.x >> BSHIFT;
            unsigned rl = (unsigned)(rc.x & (BROWS - 1));
            int p = atomicAdd(&lcur[b], 1);
            stage[p] = make_int2((int)((rl << COLBITS) | (unsigned)rc.y),
                                 __float_as_int(wv));
            dstg[p] = go[b] + (p - lo[b]);
        }
    }
    #pragma unroll
    for (int off = 32; off > 0; off >>= 1) s += __shfl_down(s, off, 64);
    if ((t & 63) == 0) atomicAdd(total, s);
    __syncthreads();
    #pragma unroll
    for (int k = 0; k < CHUNK / 256; ++k) {
        int s2 = t + k * 256;
        if (s2 < cnt) bsorted[dstg[s2]] = stage[s2];
    }
}

// K3: dense bases: sbase[b] = exclusive scan of (bcur[b] - b*slot)
__global__ __launch_bounds__(256, 1) void count_scan_kernel(
    const int* __restrict__ bcur, int* __restrict__ sbase, int nb, int slot) {
    __shared__ int ssc[256];
    int t = threadIdx.x;
    int cnt = (t < nb) ? (bcur[t] - t * slot) : 0;
    ssc[t] = cnt;
    __syncthreads();
    for (int off = 1; off < 256; off <<= 1) {
        int u = (t >= off) ? ssc[t - off] : 0;
        __syncthreads();
        ssc[t] += u;
        __syncthreads();
    }
    if (t < nb) sbase[t] = ssc[t] - cnt;
}

// K4: one block per bucket: per-row offsets in LDS + L2-local row scatter
// into DENSE sorted2 (dst base sbase[b]); writes dense offs[row] starts.
__global__ __launch_bounds__(256) void local_rowsort_kernel(
    const int2* __restrict__ bsorted, const int* __restrict__ bcur,
    const int* __restrict__ sbase, int* __restrict__ offs,
    int2* __restrict__ sorted2, int n_right, int slot) {
    __shared__ int lhist[BROWS];
    __shared__ int lcur[BROWS];
    __shared__ int ps[256];
    int b = blockIdx.x;
    int t = threadIdx.x;
    int src0 = b * slot;
    int send = min(bcur[b], src0 + slot);
    int dbase = sbase[b];
    int row0 = b << BSHIFT;
    int nrows = min(BROWS, n_right - row0);

    lhist[2 * t] = 0;
    lhist[2 * t + 1] = 0;
    __syncthreads();
    for (int e = src0 + t; e < send; e += 256)
        atomicAdd(&lhist[((unsigned)bsorted[e].x) >> COLBITS], 1);
    __syncthreads();

    int v0 = lhist[2 * t];
    int v1 = lhist[2 * t + 1];
    int pv = v0 + v1;
    ps[t] = pv;
    __syncthreads();
    for (int off = 1; off < 256; off <<= 1) {
        int u = (t >= off) ? ps[t - off] : 0;
        __syncthreads();
        ps[t] += u;
        __syncthreads();
    }
    int epair = ps[t] - pv;
    lcur[2 * t] = epair;
    lcur[2 * t + 1] = epair + v0;
    if (2 * t < nrows)     offs[row0 + 2 * t]     = dbase + epair;
    if (2 * t + 1 < nrows) offs[row0 + 2 * t + 1] = dbase + epair + v0;
    __syncthreads();

    int e = src0 + t;
    for (; e + 3 * 256 < send; e += 4 * 256) {
        int2 e0 = bsorted[e + 0 * 256];
        int2 e1 = bsorted[e + 1 * 256];
        int2 e2 = bsorted[e + 2 * 256];
        int2 e3 = bsorted[e + 3 * 256];
        int p0 = atomicAdd(&lcur[((unsigned)e0.x) >> COLBITS], 1);
        int p1 = atomicAdd(&lcur[((unsigned)e1.x) >> COLBITS], 1);
        int p2 = atomicAdd(&lcur[((unsigned)e2.x) >> COLBITS], 1);
        int p3 = atomicAdd(&lcur[((unsigned)e3.x) >> COLBITS], 1);
        sorted2[dbase + p0] = e0;
        sorted2[dbase + p1] = e1;
        sorted2[dbase + p2] = e2;
        sorted2[dbase + p3] = e3;
    }
    for (; e < send; e += 256) {
        int2 e0 = bsorted[e];
        int p0 = atomicAdd(&lcur[((unsigned)e0.x) >> COLBITS], 1);
        sorted2[dbase + p0] = e0;
    }
}

// K5: one wave per row, 8 edges per iteration, depth-1 sorted prefetch.
// lane = (sub<<3)|d8: sub = edge-in-octet, d8 = dim-octet (8 bf16 = uint4).
// One gather instruction covers 8 edges (8 x 128B). Reduce via shfl_xor
// (8/16/32); lanes 0-7 write 256B contiguous.
__global__ void seg_gather_bf16_kernel(const int2* __restrict__ sorted,
                                       const int* __restrict__ offs,
                                       const uint4* __restrict__ left16o,
                                       const float* __restrict__ right,
                                       const float* __restrict__ c,
                                       const float* __restrict__ temp,
                                       const float* __restrict__ total,
                                       float* __restrict__ hout, int n_right,
                                       int n_edges, int offs_are_ends) {
    int gid = blockIdx.x * blockDim.x + threadIdx.x;
    int wid = gid >> 6;
    int lane = gid & 63;
    if (wid >= n_right) return;
    int start, end;
    if (offs_are_ends) {
        end = offs[wid];
        start = (wid == 0) ? 0 : offs[wid - 1];
    } else {
        start = offs[wid];
        end = (wid + 1 < n_right) ? offs[wid + 1] : n_edges;
    }

    int sub = lane >> 3;       // edge within octet
    int d8  = lane & 7;        // dim octet

    float cv = c[wid];
    float inv = 1.0f / fmaxf(total[0], 1.0f);
    float t1 = temp[1];

    float a0 = 0.f, a1 = 0.f, a2 = 0.f, a3 = 0.f;
    float a4 = 0.f, a5 = 0.f, a6 = 0.f, a7 = 0.f;

    if (start < end) {
        int ee = start + sub;
        int2 sv = sorted[(ee < end) ? ee : (end - 1)];
        for (int base = start; base < end; base += 8) {
            int2 cur = sv;
            int ecur = base + sub;
            int bnext = base + 8;
            if (bnext < end) {
                int en = bnext + sub;
                sv = sorted[(en < end) ? en : (end - 1)];
            }
            float wv = (ecur < end) ? __int_as_float(cur.y) : 0.f;
            unsigned col = (unsigned)cur.x & COLMASK;
            uint4 pk = left16o[(size_t)col * 8 + d8];
            a0 = fmaf(wv, __uint_as_float(pk.x << 16), a0);
            a1 = fmaf(wv, __uint_as_float(pk.x & 0xffff0000u), a1);
            a2 = fmaf(wv, __uint_as_float(pk.y << 16), a2);
            a3 = fmaf(wv, __uint_as_float(pk.y & 0xffff0000u), a3);
            a4 = fmaf(wv, __uint_as_float(pk.z << 16), a4);
            a5 = fmaf(wv, __uint_as_float(pk.z & 0xffff0000u), a5);
            a6 = fmaf(wv, __uint_as_float(pk.w << 16), a6);
            a7 = fmaf(wv, __uint_as_float(pk.w & 0xffff0000u), a7);
        }
    }

    // reduce across the 8 edge-subgroups (lane bits 3..5)
    #define RED8(x) x += __shfl_xor(x, 8, 64); x += __shfl_xor(x, 16, 64); \
                    x += __shfl_xor(x, 32, 64);
    RED8(a0) RED8(a1) RED8(a2) RED8(a3) RED8(a4) RED8(a5) RED8(a6) RED8(a7)
    #undef RED8

    if (lane < 8) {
        const float4* rp = (const float4*)(right + (size_t)wid * EMB);
        float4 r0 = rp[2 * lane];
        float4 r1 = rp[2 * lane + 1];
        float4 h0, h1;
        h0.x = r0.x + t1 * (cv - a0 * inv);
        h0.y = r0.y + t1 * (cv - a1 * inv);
        h0.z = r0.z + t1 * (cv - a2 * inv);
        h0.w = r0.w + t1 * (cv - a3 * inv);
        h1.x = r1.x + t1 * (cv - a4 * inv);
        h1.y = r1.y + t1 * (cv - a5 * inv);
        h1.z = r1.z + t1 * (cv - a6 * inv);
        h1.w = r1.w + t1 * (cv - a7 * inv);
        float4* op = (float4*)(hout + (size_t)wid * EMB);
        op[2 * lane] = h0;
        op[2 * lane + 1] = h1;
    }
}

// K6: MLP on h (in place in io): out = relu(h@W1^T+b1)@W2^T+b2
__global__ __launch_bounds__(256, 1) void mlp_kernel(
    const float* __restrict__ W1, const float* __restrict__ b1,
    const float* __restrict__ W2, const float* __restrict__ b2,
    float* __restrict__ io, int n) {
    int r = blockIdx.x * blockDim.x + threadIdx.x;
    if (r >= n) return;

    float h[EMB];
    const float4* qp = (const float4*)(io + (size_t)r * EMB);
    #pragma unroll
    for (int q = 0; q < EMB / 4; ++q) {
        float4 qv = qp[q];
        h[4 * q + 0] = qv.x;
        h[4 * q + 1] = qv.y;
        h[4 * q + 2] = qv.z;
        h[4 * q + 3] = qv.w;
    }

    float h1[EMB];
    #pragma unroll
    for (int j = 0; j < EMB; j += 4) {
        float s0 = b1[j + 0], s1 = b1[j + 1], s2 = b1[j + 2], s3 = b1[j + 3];
        #pragma unroll
        for (int k = 0; k < EMB; ++k) {
            float hk = h[k];
            s0 = fmaf(hk, W1[(j + 0) * EMB + k], s0);
            s1 = fmaf(hk, W1[(j + 1) * EMB + k], s1);
            s2 = fmaf(hk, W1[(j + 2) * EMB + k], s2);
            s3 = fmaf(hk, W1[(j + 3) * EMB + k], s3);
        }
        h1[j + 0] = fmaxf(s0, 0.f);
        h1[j + 1] = fmaxf(s1, 0.f);
        h1[j + 2] = fmaxf(s2, 0.f);
        h1[j + 3] = fmaxf(s3, 0.f);
    }

    float4* op = (float4*)(io + (size_t)r * EMB);
    #pragma unroll
    for (int j = 0; j < EMB; j += 4) {
        float s0 = b2[j + 0], s1 = b2[j + 1], s2 = b2[j + 2], s3 = b2[j + 3];
        #pragma unroll
        for (int k = 0; k < EMB; ++k) {
            float hk = h1[k];
            s0 = fmaf(hk, W2[(j + 0) * EMB + k], s0);
            s1 = fmaf(hk, W2[(j + 1) * EMB + k], s1);
            s2 = fmaf(hk, W2[(j + 2) * EMB + k], s2);
            s3 = fmaf(hk, W2[(j + 3) * EMB + k], s3);
        }
        op[j / 4] = make_float4(s0, s1, s2, s3);
    }
}

// ===================== mid-path kernels (row-level hist + scans) ==========

__global__ void hist_total_kernel(const int2* __restrict__ eidx,
                                  const float* __restrict__ w, int n_edges,
                                  int* __restrict__ counts,
                                  float* __restrict__ total) {
    int gid = blockIdx.x * blockDim.x + threadIdx.x;
    int stride = gridDim.x * blockDim.x;
    float s = 0.f;
    for (int e = gid; e < n_edges; e += stride) {
        s += w[e];
        atomicAdd(&counts[eidx[e].x], 1);
    }
    #pragma unroll
    for (int off = 32; off > 0; off >>= 1) s += __shfl_down(s, off, 64);
    if ((threadIdx.x & 63) == 0) atomicAdd(total, s);
}

__global__ __launch_bounds__(1024, 1) void scan1_kernel(
    const int* __restrict__ cnt, int* __restrict__ incl,
    int* __restrict__ bsums, int n) {
    __shared__ int s[1024];
    int t = threadIdx.x;
    int i = blockIdx.x * 1024 + t;
    int v = (i < n) ? cnt[i] : 0;
    s[t] = v;
    __syncthreads();
    for (int off = 1; off < 1024; off <<= 1) {
        int u = (t >= off) ? s[t - off] : 0;
        __syncthreads();
        s[t] += u;
        __syncthreads();
    }
    if (i < n) incl[i] = s[t];
    if (t == 1023) bsums[blockIdx.x] = s[t];
}

__global__ __launch_bounds__(256, 1) void scan2_kernel(int* __restrict__ bsums, int nb) {
    __shared__ int s[256];
    int t = threadIdx.x;
    int v = (t < nb) ? bsums[t] : 0;
    s[t] = v;
    __syncthreads();
    for (int off = 1; off < 256; off <<= 1) {
        int u = (t >= off) ? s[t - off] : 0;
        __syncthreads();
        s[t] += u;
        __syncthreads();
    }
    if (t < nb) bsums[t] = s[t] - v;
}

__global__ void scan3_kernel(const int* __restrict__ incl,
                             const int* __restrict__ base,
                             int* __restrict__ offs, int n) {
    int i = blockIdx.x * blockDim.x + threadIdx.x;
    if (i >= n) return;
    offs[i] = (i == 0) ? 0 : incl[i - 1] + base[(i - 1) >> 10];
}

__global__ void scatter_kernel(const int2* __restrict__ eidx,
                               const float* __restrict__ w, int n_edges,
                               int* __restrict__ offs,
                               int2* __restrict__ sorted) {
    int gid = blockIdx.x * blockDim.x + threadIdx.x;
    int stride = gridDim.x * blockDim.x;
    for (int e = gid; e < n_edges; e += stride) {
        int2 rc = eidx[e];
        float v = w[e];
        int pos = atomicAdd(&offs[rc.x], 1);
        sorted[pos] = make_int2(rc.y, __float_as_int(v));
    }
}

// ===================== fallback (atomic path) =====================

__global__ void sum_weights_kernel(const float* __restrict__ w, int n,
                                   float* __restrict__ total) {
    int gid = blockIdx.x * blockDim.x + threadIdx.x;
    int stride = gridDim.x * blockDim.x;
    float s = 0.f;
    for (int i = gid; i < n; i += stride) s += w[i];
    #pragma unroll
    for (int off = 32; off > 0; off >>= 1) s += __shfl_down(s, off, 64);
    if ((threadIdx.x & 63) == 0) atomicAdd(total, s);
}

__global__ void edge_scatter_kernel(const int* __restrict__ idx,
                                    const float* __restrict__ w,
                                    const float* __restrict__ left,
                                    const float* __restrict__ total,
                                    float* __restrict__ conv,
                                    long long n_threads) {
    long long gid = (long long)blockIdx.x * blockDim.x + threadIdx.x;
    if (gid >= n_threads) return;
    int e = (int)(gid >> 6);
    int d = (int)(gid & 63);
    float inv = 1.0f / fmaxf(total[0], 1.0f);
    int row = idx[2 * e];
    int col = idx[2 * e + 1];
    float v = w[e] * inv;
    float msg = left[(size_t)col * EMB + d] * v;
    atomicAdd(&conv[(size_t)row * EMB + d], msg);
}

__global__ __launch_bounds__(256, 1) void fused_mlp_kernel(
    const float* __restrict__ right, const float* __restrict__ c,
    const float* __restrict__ temp,
    const float* __restrict__ W1, const float* __restrict__ b1,
    const float* __restrict__ W2, const float* __restrict__ b2,
    float* __restrict__ io, int n) {
    int r = blockIdx.x * blockDim.x + threadIdx.x;
    if (r >= n) return;
    float t1 = temp[1];
    float cv = c[r];
    float h[EMB];
    const float4* rp = (const float4*)(right + (size_t)r * EMB);
    const float4* qp = (const float4*)(io + (size_t)r * EMB);
    #pragma unroll
    for (int q = 0; q < EMB / 4; ++q) {
        float4 rv = rp[q];
        float4 qv = qp[q];
        h[4 * q + 0] = rv.x + t1 * (cv - qv.x);
        h[4 * q + 1] = rv.y + t1 * (cv - qv.y);
        h[4 * q + 2] = rv.z + t1 * (cv - qv.z);
        h[4 * q + 3] = rv.w + t1 * (cv - qv.w);
    }
    float h1[EMB];
    #pragma unroll
    for (int j = 0; j < EMB; j += 4) {
        float s0 = b1[j], s1 = b1[j + 1], s2 = b1[j + 2], s3 = b1[j + 3];
        #pragma unroll
        for (int k = 0; k < EMB; ++k) {
            float hk = h[k];
            s0 = fmaf(hk, W1[(j + 0) * EMB + k], s0);
            s1 = fmaf(hk, W1[(j + 1) * EMB + k], s1);
            s2 = fmaf(hk, W1[(j + 2) * EMB + k], s2);
            s3 = fmaf(hk, W1[(j + 3) * EMB + k], s3);
        }
        h1[j] = fmaxf(s0, 0.f);
        h1[j + 1] = fmaxf(s1, 0.f);
        h1[j + 2] = fmaxf(s2, 0.f);
        h1[j + 3] = fmaxf(s3, 0.f);
    }
    float4* op = (float4*)(io + (size_t)r * EMB);
    #pragma unroll
    for (int j = 0; j < EMB; j += 4) {
        float s0 = b2[j], s1 = b2[j + 1], s2 = b2[j + 2], s3 = b2[j + 3];
        #pragma unroll
        for (int k = 0; k < EMB; ++k) {
            float hk = h1[k];
            s0 = fmaf(hk, W2[(j + 0) * EMB + k], s0);
            s1 = fmaf(hk, W2[(j + 1) * EMB + k], s1);
            s2 = fmaf(hk, W2[(j + 2) * EMB + k], s2);
            s3 = fmaf(hk, W2[(j + 3) * EMB + k], s3);
        }
        op[j / 4] = make_float4(s0, s1, s2, s3);
    }
}

// ===================== launch =====================

extern "C" void kernel_launch(void* const* d_in, const int* in_sizes, int n_in,
                              void* d_out, int out_size, void* d_ws, size_t ws_size,
                              hipStream_t stream) {
    const float* left   = (const float*)d_in[0];
    const int*   eidx   = (const int*)d_in[2];
    const float* ew     = (const float*)d_in[3];
    const float* right  = (const float*)d_in[4];
    const float* c      = (const float*)d_in[5];
    const float* temp   = (const float*)d_in[7];
    const float* W1     = (const float*)d_in[8];
    const float* b1     = (const float*)d_in[9];
    const float* W2     = (const float*)d_in[10];
    const float* b2     = (const float*)d_in[11];

    const int n_edges = in_sizes[3];
    const int n_right = in_sizes[4] / EMB;
    const int n_left  = in_sizes[0] / EMB;
    float* out = (float*)d_out;

    const int nb = (n_right + BROWS - 1) >> BSHIFT;
    const int nblocks_scan = (n_right + 1023) / 1024;

    auto align256 = [](size_t x) { return (x + 255) & ~(size_t)255; };

    // slack slot per bucket: avg + avg/16 + 128 (~8 sigma for Poisson spread)
    int slot = n_edges / (nb > 0 ? nb : 1);
    slot += slot / 16 + 128;

    // full-path layout: total | bcur(nb) | sbase(nb+1) | offs(n_right)
    //                 | bsorted(nb*slot + slot pad) | sorted2(n_edges) | left16
    size_t off_bcur    = 64;
    size_t off_sbase   = align256(off_bcur + (size_t)nb * 4);
    size_t off_offs    = align256(off_sbase + (size_t)(nb + 1) * 4);
    size_t off_bsorted = align256(off_offs + (size_t)n_right * 4);
    size_t off_sorted2 = align256(off_bsorted + ((size_t)nb * slot + slot) * 8);
    size_t off_left16f = align256(off_sorted2 + (size_t)n_edges * 8);
    size_t req_full    = off_left16f + (size_t)n_left * EMB * 2;

    // mid-path layout: total | offs | incl | bsum | sorted | left16
    size_t m_off_offs   = 64;
    size_t m_off_incl   = align256(m_off_offs + (size_t)n_right * 4);
    size_t m_off_bsum   = align256(m_off_incl + (size_t)n_right * 4);
    size_t m_off_sorted = align256(m_off_bsum + 1024);
    size_t m_off_left16 = align256(m_off_sorted + (size_t)n_edges * 8);
    size_t req_mid      = m_off_left16 + (size_t)n_left * EMB * 2;

    bool common_ok = (nb <= 256) && (nblocks_scan <= 256) &&
                     (n_left <= (1 << COLBITS)) && (BROWS * nb >= n_right);

    if (common_ok && ws_size >= req_full) {
        // ---------- full path ----------
        char* ws = (char*)d_ws;
        float* total = (float*)ws;
        int* bcur = (int*)(ws + off_bcur);
        int* sbase = (int*)(ws + off_sbase);
        int* offs = (int*)(ws + off_offs);
        int2* bsorted = (int2*)(ws + off_bsorted);
        int2* sorted2 = (int2*)(ws + off_sorted2);
        unsigned short* left16 = (unsigned short*)(ws + off_left16f);

        hipMemsetAsync(ws, 0, 64, stream);  // total

        int n2 = n_left * EMB / 2;
        convert_left_kernel<<<(n2 + 255) / 256, 256, 0, stream>>>(
            left, (unsigned*)left16, n2);
        init_bcur_kernel<<<1, 256, 0, stream>>>(bcur, nb, slot);
        {
            int nchunks = (n_edges + CHUNK - 1) / CHUNK;
            partition_kernel<<<nchunks, 256, 0, stream>>>(
                (const int2*)eidx, ew, n_edges, bcur, bsorted, total);
        }
        count_scan_kernel<<<1, 256, 0, stream>>>(bcur, sbase, nb, slot);
        local_rowsort_kernel<<<nb, 256, 0, stream>>>(bsorted, bcur, sbase, offs,
                                                     sorted2, n_right, slot);
        {
            long long n_threads = (long long)n_right * EMB;
            int blocks = (int)((n_threads + 255) / 256);
            seg_gather_bf16_kernel<<<blocks, 256, 0, stream>>>(
                sorted2, offs, (const uint4*)left16, right, c, temp, total,
                out, n_right, n_edges, 0);
        }
        mlp_kernel<<<(n_right + 255) / 256, 256, 0, stream>>>(W1, b1, W2, b2,
                                                              out, n_right);
    } else if (common_ok && ws_size >= req_mid) {
        // ---------- mid path: round-3 proven structure ----------
        char* ws = (char*)d_ws;
        float* total = (float*)ws;
        int* offs = (int*)(ws + m_off_offs);
        int* incl = (int*)(ws + m_off_incl);
        int* bsum = (int*)(ws + m_off_bsum);
        int2* sorted = (int2*)(ws + m_off_sorted);
        unsigned short* left16 = (unsigned short*)(ws + m_off_left16);

        hipMemsetAsync(ws, 0, m_off_offs + (size_t)n_right * 4, stream);

        int n2 = n_left * EMB / 2;
        convert_left_kernel<<<(n2 + 255) / 256, 256, 0, stream>>>(
            left, (unsigned*)left16, n2);
        hist_total_kernel<<<2048, 256, 0, stream>>>((const int2*)eidx, ew,
                                                    n_edges, offs, total);
        scan1_kernel<<<nblocks_scan, 1024, 0, stream>>>(offs, incl, bsum, n_right);
        scan2_kernel<<<1, 256, 0, stream>>>(bsum, nblocks_scan);
        scan3_kernel<<<(n_right + 255) / 256, 256, 0, stream>>>(incl, bsum, offs,
                                                                n_right);
        scatter_kernel<<<2048, 256, 0, stream>>>((const int2*)eidx, ew, n_edges,
                                                 offs, sorted);
        {
            long long n_threads = (long long)n_right * EMB;
            int blocks = (int)((n_threads + 255) / 256);
            seg_gather_bf16_kernel<<<blocks, 256, 0, stream>>>(
                sorted, offs, (const uint4*)left16, right, c, temp, total,
                out, n_right, n_edges, 1);
        }
        mlp_kernel<<<(n_right + 255) / 256, 256, 0, stream>>>(W1, b1, W2, b2,
                                                              out, n_right);
    } else {
        // ---------- fallback: atomic path ----------
        float* total = (float*)d_ws;
        hipMemsetAsync(d_out, 0, (size_t)out_size * sizeof(float), stream);
        hipMemsetAsync(d_ws, 0, sizeof(float), stream);
        sum_weights_kernel<<<2048, 256, 0, stream>>>(ew, n_edges, total);
        long long n_threads = (long long)n_edges * EMB;
        long long blocks = (n_threads + 255) / 256;
        edge_scatter_kernel<<<(int)blocks, 256, 0, stream>>>(
            eidx, ew, left, total, out, n_threads);
        int mblocks = (n_right + 255) / 256;
        fused_mlp_kernel<<<mblocks, 256, 0, stream>>>(right, c, temp, W1, b1, W2,
                                                      b2, out, n_right);
    }
}

// Round 9
// 255.375 us; speedup vs baseline: 5.9958x; 1.0942x over previous
//
#include <hip/hip_runtime.h>

#define EMB 64
#define BROWS 512            // rows per bucket
#define BSHIFT 9             // log2(BROWS)
#define CHUNK 4096           // edges per partition block
#define COLBITS 23
#define COLMASK ((1u << COLBITS) - 1u)
#define MROWS 64             // rows per MLP block
#define HPAD 66              // padded stride for hT

// bf16 pack (RNE)
__device__ __forceinline__ unsigned short f2bf(float f) {
    unsigned u = __float_as_uint(f);
    u = u + 0x7FFFu + ((u >> 16) & 1u);
    return (unsigned short)(u >> 16);
}

// K0: convert left (f32) -> left16 (bf16), 2 elems/thread
__global__ void convert_left_kernel(const float* __restrict__ left,
                                    unsigned* __restrict__ left16, int n2) {
    int i = blockIdx.x * blockDim.x + threadIdx.x;
    if (i >= n2) return;
    float2 v = ((const float2*)left)[i];
    left16[i] = (unsigned)f2bf(v.x) | ((unsigned)f2bf(v.y) << 16);
}

// K1: bcur[b] = b*slot
__global__ void init_bcur_kernel(int* __restrict__ bcur, int nb, int slot) {
    int t = threadIdx.x;
    if (t < nb) bcur[t] = t * slot;
}

// K2: partition edges into slack-slotted buckets (LDS-staged coalesced writes)
// and compute total = sum(w). bsorted[i] = ((row_local<<COLBITS)|col, bits(w)).
__global__ __launch_bounds__(256) void partition_kernel(
    const int2* __restrict__ eidx, const float* __restrict__ w, int n_edges,
    int* __restrict__ bcursor, int2* __restrict__ bsorted,
    float* __restrict__ total) {
    __shared__ int lh[256];
    __shared__ int lo[256];
    __shared__ int go[256];
    __shared__ int lcur[256];
    __shared__ int2 stage[CHUNK];
    __shared__ int dstg[CHUNK];
    int t = threadIdx.x;
    int base = blockIdx.x * CHUNK;
    int cnt = min(CHUNK, n_edges - base);

    lh[t] = 0;
    __syncthreads();
    #pragma unroll
    for (int k = 0; k < CHUNK / 256; ++k) {
        int e = base + t + k * 256;
        if (e < n_edges) atomicAdd(&lh[eidx[e].x >> BSHIFT], 1);
    }
    __syncthreads();
    int v = lh[t];
    lo[t] = v;
    __syncthreads();
    for (int off = 1; off < 256; off <<= 1) {
        int u = (t >= off) ? lo[t - off] : 0;
        __syncthreads();
        lo[t] += u;
        __syncthreads();
    }
    int excl = lo[t] - v;
    go[t] = (v > 0) ? atomicAdd(&bcursor[t], v) : 0;
    __syncthreads();
    lo[t] = excl;
    lcur[t] = excl;
    __syncthreads();

    float s = 0.f;
    #pragma unroll
    for (int k = 0; k < CHUNK / 256; ++k) {
        int e = base + t + k * 256;
        if (e < n_edges) {
            int2 rc = eidx[e];
            float wv = w[e];
            s += wv;
            int b = rc.x >> BSHIFT;
            unsigned rl = (unsigned)(rc.x & (BROWS - 1));
            int p = atomicAdd(&lcur[b], 1);
            stage[p] = make_int2((int)((rl << COLBITS) | (unsigned)rc.y),
                                 __float_as_int(wv));
            dstg[p] = go[b] + (p - lo[b]);
        }
    }
    #pragma unroll
    for (int off = 32; off > 0; off >>= 1) s += __shfl_down(s, off, 64);
    if ((t & 63) == 0) atomicAdd(total, s);
    __syncthreads();
    #pragma unroll
    for (int k = 0; k < CHUNK / 256; ++k) {
        int s2 = t + k * 256;
        if (s2 < cnt) bsorted[dstg[s2]] = stage[s2];
    }
}

// K3: dense bases: sbase[b] = exclusive scan of (bcur[b] - b*slot)
__global__ __launch_bounds__(256, 1) void count_scan_kernel(
    const int* __restrict__ bcur, int* __restrict__ sbase, int nb, int slot) {
    __shared__ int ssc[256];
    int t = threadIdx.x;
    int cnt = (t < nb) ? (bcur[t] - t * slot) : 0;
    ssc[t] = cnt;
    __syncthreads();
    for (int off = 1; off < 256; off <<= 1) {
        int u = (t >= off) ? ssc[t - off] : 0;
        __syncthreads();
        ssc[t] += u;
        __syncthreads();
    }
    if (t < nb) sbase[t] = ssc[t] - cnt;
}

// K4: one block per bucket: per-row offsets in LDS + L2-local row scatter
// into DENSE sorted2 (dst base sbase[b]); writes dense offs[row] starts.
__global__ __launch_bounds__(256) void local_rowsort_kernel(
    const int2* __restrict__ bsorted, const int* __restrict__ bcur,
    const int* __restrict__ sbase, int* __restrict__ offs,
    int2* __restrict__ sorted2, int n_right, int slot) {
    __shared__ int lhist[BROWS];
    __shared__ int lcur[BROWS];
    __shared__ int ps[256];
    int b = blockIdx.x;
    int t = threadIdx.x;
    int src0 = b * slot;
    int send = min(bcur[b], src0 + slot);
    int dbase = sbase[b];
    int row0 = b << BSHIFT;
    int nrows = min(BROWS, n_right - row0);

    lhist[2 * t] = 0;
    lhist[2 * t + 1] = 0;
    __syncthreads();
    for (int e = src0 + t; e < send; e += 256)
        atomicAdd(&lhist[((unsigned)bsorted[e].x) >> COLBITS], 1);
    __syncthreads();

    int v0 = lhist[2 * t];
    int v1 = lhist[2 * t + 1];
    int pv = v0 + v1;
    ps[t] = pv;
    __syncthreads();
    for (int off = 1; off < 256; off <<= 1) {
        int u = (t >= off) ? ps[t - off] : 0;
        __syncthreads();
        ps[t] += u;
        __syncthreads();
    }
    int epair = ps[t] - pv;
    lcur[2 * t] = epair;
    lcur[2 * t + 1] = epair + v0;
    if (2 * t < nrows)     offs[row0 + 2 * t]     = dbase + epair;
    if (2 * t + 1 < nrows) offs[row0 + 2 * t + 1] = dbase + epair + v0;
    __syncthreads();

    int e = src0 + t;
    for (; e + 3 * 256 < send; e += 4 * 256) {
        int2 e0 = bsorted[e + 0 * 256];
        int2 e1 = bsorted[e + 1 * 256];
        int2 e2 = bsorted[e + 2 * 256];
        int2 e3 = bsorted[e + 3 * 256];
        int p0 = atomicAdd(&lcur[((unsigned)e0.x) >> COLBITS], 1);
        int p1 = atomicAdd(&lcur[((unsigned)e1.x) >> COLBITS], 1);
        int p2 = atomicAdd(&lcur[((unsigned)e2.x) >> COLBITS], 1);
        int p3 = atomicAdd(&lcur[((unsigned)e3.x) >> COLBITS], 1);
        sorted2[dbase + p0] = e0;
        sorted2[dbase + p1] = e1;
        sorted2[dbase + p2] = e2;
        sorted2[dbase + p3] = e3;
    }
    for (; e < send; e += 256) {
        int2 e0 = bsorted[e];
        int p0 = atomicAdd(&lcur[((unsigned)e0.x) >> COLBITS], 1);
        sorted2[dbase + p0] = e0;
    }
}

// K5: one wave per row, 8 edges per iteration, depth-1 sorted prefetch.
__global__ void seg_gather_bf16_kernel(const int2* __restrict__ sorted,
                                       const int* __restrict__ offs,
                                       const uint4* __restrict__ left16o,
                                       const float* __restrict__ right,
                                       const float* __restrict__ c,
                                       const float* __restrict__ temp,
                                       const float* __restrict__ total,
                                       float* __restrict__ hout, int n_right,
                                       int n_edges, int offs_are_ends) {
    int gid = blockIdx.x * blockDim.x + threadIdx.x;
    int wid = gid >> 6;
    int lane = gid & 63;
    if (wid >= n_right) return;
    int start, end;
    if (offs_are_ends) {
        end = offs[wid];
        start = (wid == 0) ? 0 : offs[wid - 1];
    } else {
        start = offs[wid];
        end = (wid + 1 < n_right) ? offs[wid + 1] : n_edges;
    }

    int sub = lane >> 3;       // edge within octet
    int d8  = lane & 7;        // dim octet

    float cv = c[wid];
    float inv = 1.0f / fmaxf(total[0], 1.0f);
    float t1 = temp[1];

    float a0 = 0.f, a1 = 0.f, a2 = 0.f, a3 = 0.f;
    float a4 = 0.f, a5 = 0.f, a6 = 0.f, a7 = 0.f;

    if (start < end) {
        int ee = start + sub;
        int2 sv = sorted[(ee < end) ? ee : (end - 1)];
        for (int base = start; base < end; base += 8) {
            int2 cur = sv;
            int ecur = base + sub;
            int bnext = base + 8;
            if (bnext < end) {
                int en = bnext + sub;
                sv = sorted[(en < end) ? en : (end - 1)];
            }
            float wv = (ecur < end) ? __int_as_float(cur.y) : 0.f;
            unsigned col = (unsigned)cur.x & COLMASK;
            uint4 pk = left16o[(size_t)col * 8 + d8];
            a0 = fmaf(wv, __uint_as_float(pk.x << 16), a0);
            a1 = fmaf(wv, __uint_as_float(pk.x & 0xffff0000u), a1);
            a2 = fmaf(wv, __uint_as_float(pk.y << 16), a2);
            a3 = fmaf(wv, __uint_as_float(pk.y & 0xffff0000u), a3);
            a4 = fmaf(wv, __uint_as_float(pk.z << 16), a4);
            a5 = fmaf(wv, __uint_as_float(pk.z & 0xffff0000u), a5);
            a6 = fmaf(wv, __uint_as_float(pk.w << 16), a6);
            a7 = fmaf(wv, __uint_as_float(pk.w & 0xffff0000u), a7);
        }
    }

    #define RED8(x) x += __shfl_xor(x, 8, 64); x += __shfl_xor(x, 16, 64); \
                    x += __shfl_xor(x, 32, 64);
    RED8(a0) RED8(a1) RED8(a2) RED8(a3) RED8(a4) RED8(a5) RED8(a6) RED8(a7)
    #undef RED8

    if (lane < 8) {
        const float4* rp = (const float4*)(right + (size_t)wid * EMB);
        float4 r0 = rp[2 * lane];
        float4 r1 = rp[2 * lane + 1];
        float4 h0, h1;
        h0.x = r0.x + t1 * (cv - a0 * inv);
        h0.y = r0.y + t1 * (cv - a1 * inv);
        h0.z = r0.z + t1 * (cv - a2 * inv);
        h0.w = r0.w + t1 * (cv - a3 * inv);
        h1.x = r1.x + t1 * (cv - a4 * inv);
        h1.y = r1.y + t1 * (cv - a5 * inv);
        h1.z = r1.z + t1 * (cv - a6 * inv);
        h1.w = r1.w + t1 * (cv - a7 * inv);
        float4* op = (float4*)(hout + (size_t)wid * EMB);
        op[2 * lane] = h0;
        op[2 * lane + 1] = h1;
    }
}

// K6: tiled MLP. Block = 256 threads = 64-row tile; thread (r=t&63, q=t>>6)
// computes outputs j in [16q, 16q+16). h exchanged transposed via LDS;
// W1/W2 via wave-uniform s_loads (readfirstlane(q)); in-place on io.
__global__ __launch_bounds__(256, 4) void mlp_kernel(
    const float* __restrict__ W1, const float* __restrict__ b1,
    const float* __restrict__ W2, const float* __restrict__ b2,
    float* __restrict__ io, int n) {
    __shared__ float hT[64 * HPAD];    // hT[c][r'], stride HPAD
    __shared__ float h1T[64 * 64];     // h1T[j][r']
    int t = threadIdx.x;
    int r = t & 63;
    int q = __builtin_amdgcn_readfirstlane(t >> 6);   // wave-uniform 0..3
    int row0 = blockIdx.x * MROWS;

    // stage h tile transposed (coalesced global reads)
    #pragma unroll
    for (int i = 0; i < 16; ++i) {
        int rr = i * 4 + q;
        int gr = row0 + rr;
        float v = (gr < n) ? io[(size_t)gr * EMB + r] : 0.f;
        hT[r * HPAD + rr] = v;
    }
    __syncthreads();

    // layer 1: acc[jj] = b1 + sum_k h[k] * W1[j][k]
    float acc[16];
    #pragma unroll
    for (int jj = 0; jj < 16; ++jj) acc[jj] = b1[q * 16 + jj];
    for (int k = 0; k < 64; ++k) {
        float hk = hT[k * HPAD + r];
        #pragma unroll
        for (int jj = 0; jj < 16; ++jj)
            acc[jj] = fmaf(hk, W1[(q * 16 + jj) * EMB + k], acc[jj]);
    }
    #pragma unroll
    for (int jj = 0; jj < 16; ++jj)
        h1T[(q * 16 + jj) * 64 + r] = fmaxf(acc[jj], 0.f);
    __syncthreads();

    // layer 2
    #pragma unroll
    for (int jj = 0; jj < 16; ++jj) acc[jj] = b2[q * 16 + jj];
    for (int k = 0; k < 64; ++k) {
        float hk = h1T[k * 64 + r];
        #pragma unroll
        for (int jj = 0; jj < 16; ++jj)
            acc[jj] = fmaf(hk, W2[(q * 16 + jj) * EMB + k], acc[jj]);
    }
    __syncthreads();                    // hT reusable now
    #pragma unroll
    for (int jj = 0; jj < 16; ++jj)
        hT[(q * 16 + jj) * HPAD + r] = acc[jj];   // outT[j][r']... j=col
    __syncthreads();

    // coalesced write-out (inverse of staging mapping)
    #pragma unroll
    for (int i = 0; i < 16; ++i) {
        int rr = i * 4 + q;
        int gr = row0 + rr;
        if (gr < n) io[(size_t)gr * EMB + r] = hT[r * HPAD + rr];
    }
}

// ===================== mid-path kernels (row-level hist + scans) ==========

__global__ void hist_total_kernel(const int2* __restrict__ eidx,
                                  const float* __restrict__ w, int n_edges,
                                  int* __restrict__ counts,
                                  float* __restrict__ total) {
    int gid = blockIdx.x * blockDim.x + threadIdx.x;
    int stride = gridDim.x * blockDim.x;
    float s = 0.f;
    for (int e = gid; e < n_edges; e += stride) {
        s += w[e];
        atomicAdd(&counts[eidx[e].x], 1);
    }
    #pragma unroll
    for (int off = 32; off > 0; off >>= 1) s += __shfl_down(s, off, 64);
    if ((threadIdx.x & 63) == 0) atomicAdd(total, s);
}

__global__ __launch_bounds__(1024, 1) void scan1_kernel(
    const int* __restrict__ cnt, int* __restrict__ incl,
    int* __restrict__ bsums, int n) {
    __shared__ int s[1024];
    int t = threadIdx.x;
    int i = blockIdx.x * 1024 + t;
    int v = (i < n) ? cnt[i] : 0;
    s[t] = v;
    __syncthreads();
    for (int off = 1; off < 1024; off <<= 1) {
        int u = (t >= off) ? s[t - off] : 0;
        __syncthreads();
        s[t] += u;
        __syncthreads();
    }
    if (i < n) incl[i] = s[t];
    if (t == 1023) bsums[blockIdx.x] = s[t];
}

__global__ __launch_bounds__(256, 1) void scan2_kernel(int* __restrict__ bsums, int nb) {
    __shared__ int s[256];
    int t = threadIdx.x;
    int v = (t < nb) ? bsums[t] : 0;
    s[t] = v;
    __syncthreads();
    for (int off = 1; off < 256; off <<= 1) {
        int u = (t >= off) ? s[t - off] : 0;
        __syncthreads();
        s[t] += u;
        __syncthreads();
    }
    if (t < nb) bsums[t] = s[t] - v;
}

__global__ void scan3_kernel(const int* __restrict__ incl,
                             const int* __restrict__ base,
                             int* __restrict__ offs, int n) {
    int i = blockIdx.x * blockDim.x + threadIdx.x;
    if (i >= n) return;
    offs[i] = (i == 0) ? 0 : incl[i - 1] + base[(i - 1) >> 10];
}

__global__ void scatter_kernel(const int2* __restrict__ eidx,
                               const float* __restrict__ w, int n_edges,
                               int* __restrict__ offs,
                               int2* __restrict__ sorted) {
    int gid = blockIdx.x * blockDim.x + threadIdx.x;
    int stride = gridDim.x * blockDim.x;
    for (int e = gid; e < n_edges; e += stride) {
        int2 rc = eidx[e];
        float v = w[e];
        int pos = atomicAdd(&offs[rc.x], 1);
        sorted[pos] = make_int2(rc.y, __float_as_int(v));
    }
}

// ===================== fallback (atomic path) =====================

__global__ void sum_weights_kernel(const float* __restrict__ w, int n,
                                   float* __restrict__ total) {
    int gid = blockIdx.x * blockDim.x + threadIdx.x;
    int stride = gridDim.x * blockDim.x;
    float s = 0.f;
    for (int i = gid; i < n; i += stride) s += w[i];
    #pragma unroll
    for (int off = 32; off > 0; off >>= 1) s += __shfl_down(s, off, 64);
    if ((threadIdx.x & 63) == 0) atomicAdd(total, s);
}

__global__ void edge_scatter_kernel(const int* __restrict__ idx,
                                    const float* __restrict__ w,
                                    const float* __restrict__ left,
                                    const float* __restrict__ total,
                                    float* __restrict__ conv,
                                    long long n_threads) {
    long long gid = (long long)blockIdx.x * blockDim.x + threadIdx.x;
    if (gid >= n_threads) return;
    int e = (int)(gid >> 6);
    int d = (int)(gid & 63);
    float inv = 1.0f / fmaxf(total[0], 1.0f);
    int row = idx[2 * e];
    int col = idx[2 * e + 1];
    float v = w[e] * inv;
    float msg = left[(size_t)col * EMB + d] * v;
    atomicAdd(&conv[(size_t)row * EMB + d], msg);
}

__global__ __launch_bounds__(256, 1) void fused_mlp_kernel(
    const float* __restrict__ right, const float* __restrict__ c,
    const float* __restrict__ temp,
    const float* __restrict__ W1, const float* __restrict__ b1,
    const float* __restrict__ W2, const float* __restrict__ b2,
    float* __restrict__ io, int n) {
    int r = blockIdx.x * blockDim.x + threadIdx.x;
    if (r >= n) return;
    float t1 = temp[1];
    float cv = c[r];
    float h[EMB];
    const float4* rp = (const float4*)(right + (size_t)r * EMB);
    const float4* qp = (const float4*)(io + (size_t)r * EMB);
    #pragma unroll
    for (int qq = 0; qq < EMB / 4; ++qq) {
        float4 rv = rp[qq];
        float4 qv = qp[qq];
        h[4 * qq + 0] = rv.x + t1 * (cv - qv.x);
        h[4 * qq + 1] = rv.y + t1 * (cv - qv.y);
        h[4 * qq + 2] = rv.z + t1 * (cv - qv.z);
        h[4 * qq + 3] = rv.w + t1 * (cv - qv.w);
    }
    float h1[EMB];
    #pragma unroll
    for (int j = 0; j < EMB; j += 4) {
        float s0 = b1[j], s1 = b1[j + 1], s2 = b1[j + 2], s3 = b1[j + 3];
        #pragma unroll
        for (int k = 0; k < EMB; ++k) {
            float hk = h[k];
            s0 = fmaf(hk, W1[(j + 0) * EMB + k], s0);
            s1 = fmaf(hk, W1[(j + 1) * EMB + k], s1);
            s2 = fmaf(hk, W1[(j + 2) * EMB + k], s2);
            s3 = fmaf(hk, W1[(j + 3) * EMB + k], s3);
        }
        h1[j] = fmaxf(s0, 0.f);
        h1[j + 1] = fmaxf(s1, 0.f);
        h1[j + 2] = fmaxf(s2, 0.f);
        h1[j + 3] = fmaxf(s3, 0.f);
    }
    float4* op = (float4*)(io + (size_t)r * EMB);
    #pragma unroll
    for (int j = 0; j < EMB; j += 4) {
        float s0 = b2[j], s1 = b2[j + 1], s2 = b2[j + 2], s3 = b2[j + 3];
        #pragma unroll
        for (int k = 0; k < EMB; ++k) {
            float hk = h1[k];
            s0 = fmaf(hk, W2[(j + 0) * EMB + k], s0);
            s1 = fmaf(hk, W2[(j + 1) * EMB + k], s1);
            s2 = fmaf(hk, W2[(j + 2) * EMB + k], s2);
            s3 = fmaf(hk, W2[(j + 3) * EMB + k], s3);
        }
        op[j / 4] = make_float4(s0, s1, s2, s3);
    }
}

// ===================== launch =====================

extern "C" void kernel_launch(void* const* d_in, const int* in_sizes, int n_in,
                              void* d_out, int out_size, void* d_ws, size_t ws_size,
                              hipStream_t stream) {
    const float* left   = (const float*)d_in[0];
    const int*   eidx   = (const int*)d_in[2];
    const float* ew     = (const float*)d_in[3];
    const float* right  = (const float*)d_in[4];
    const float* c      = (const float*)d_in[5];
    const float* temp   = (const float*)d_in[7];
    const float* W1     = (const float*)d_in[8];
    const float* b1     = (const float*)d_in[9];
    const float* W2     = (const float*)d_in[10];
    const float* b2     = (const float*)d_in[11];

    const int n_edges = in_sizes[3];
    const int n_right = in_sizes[4] / EMB;
    const int n_left  = in_sizes[0] / EMB;
    float* out = (float*)d_out;

    const int nb = (n_right + BROWS - 1) >> BSHIFT;
    const int nblocks_scan = (n_right + 1023) / 1024;

    auto align256 = [](size_t x) { return (x + 255) & ~(size_t)255; };

    int slot = n_edges / (nb > 0 ? nb : 1);
    slot += slot / 16 + 128;

    size_t off_bcur    = 64;
    size_t off_sbase   = align256(off_bcur + (size_t)nb * 4);
    size_t off_offs    = align256(off_sbase + (size_t)(nb + 1) * 4);
    size_t off_bsorted = align256(off_offs + (size_t)n_right * 4);
    size_t off_sorted2 = align256(off_bsorted + ((size_t)nb * slot + slot) * 8);
    size_t off_left16f = align256(off_sorted2 + (size_t)n_edges * 8);
    size_t req_full    = off_left16f + (size_t)n_left * EMB * 2;

    size_t m_off_offs   = 64;
    size_t m_off_incl   = align256(m_off_offs + (size_t)n_right * 4);
    size_t m_off_bsum   = align256(m_off_incl + (size_t)n_right * 4);
    size_t m_off_sorted = align256(m_off_bsum + 1024);
    size_t m_off_left16 = align256(m_off_sorted + (size_t)n_edges * 8);
    size_t req_mid      = m_off_left16 + (size_t)n_left * EMB * 2;

    bool common_ok = (nb <= 256) && (nblocks_scan <= 256) &&
                     (n_left <= (1 << COLBITS)) && (BROWS * nb >= n_right);

    if (common_ok && ws_size >= req_full) {
        // ---------- full path ----------
        char* ws = (char*)d_ws;
        float* total = (float*)ws;
        int* bcur = (int*)(ws + off_bcur);
        int* sbase = (int*)(ws + off_sbase);
        int* offs = (int*)(ws + off_offs);
        int2* bsorted = (int2*)(ws + off_bsorted);
        int2* sorted2 = (int2*)(ws + off_sorted2);
        unsigned short* left16 = (unsigned short*)(ws + off_left16f);

        hipMemsetAsync(ws, 0, 64, stream);  // total

        int n2 = n_left * EMB / 2;
        convert_left_kernel<<<(n2 + 255) / 256, 256, 0, stream>>>(
            left, (unsigned*)left16, n2);
        init_bcur_kernel<<<1, 256, 0, stream>>>(bcur, nb, slot);
        {
            int nchunks = (n_edges + CHUNK - 1) / CHUNK;
            partition_kernel<<<nchunks, 256, 0, stream>>>(
                (const int2*)eidx, ew, n_edges, bcur, bsorted, total);
        }
        count_scan_kernel<<<1, 256, 0, stream>>>(bcur, sbase, nb, slot);
        local_rowsort_kernel<<<nb, 256, 0, stream>>>(bsorted, bcur, sbase, offs,
                                                     sorted2, n_right, slot);
        {
            long long n_threads = (long long)n_right * EMB;
            int blocks = (int)((n_threads + 255) / 256);
            seg_gather_bf16_kernel<<<blocks, 256, 0, stream>>>(
                sorted2, offs, (const uint4*)left16, right, c, temp, total,
                out, n_right, n_edges, 0);
        }
        mlp_kernel<<<(n_right + MROWS - 1) / MROWS, 256, 0, stream>>>(
            W1, b1, W2, b2, out, n_right);
    } else if (common_ok && ws_size >= req_mid) {
        // ---------- mid path ----------
        char* ws = (char*)d_ws;
        float* total = (float*)ws;
        int* offs = (int*)(ws + m_off_offs);
        int* incl = (int*)(ws + m_off_incl);
        int* bsum = (int*)(ws + m_off_bsum);
        int2* sorted = (int2*)(ws + m_off_sorted);
        unsigned short* left16 = (unsigned short*)(ws + m_off_left16);

        hipMemsetAsync(ws, 0, m_off_offs + (size_t)n_right * 4, stream);

        int n2 = n_left * EMB / 2;
        convert_left_kernel<<<(n2 + 255) / 256, 256, 0, stream>>>(
            left, (unsigned*)left16, n2);
        hist_total_kernel<<<2048, 256, 0, stream>>>((const int2*)eidx, ew,
                                                    n_edges, offs, total);
        scan1_kernel<<<nblocks_scan, 1024, 0, stream>>>(offs, incl, bsum, n_right);
        scan2_kernel<<<1, 256, 0, stream>>>(bsum, nblocks_scan);
        scan3_kernel<<<(n_right + 255) / 256, 256, 0, stream>>>(incl, bsum, offs,
                                                                n_right);
        scatter_kernel<<<2048, 256, 0, stream>>>((const int2*)eidx, ew, n_edges,
                                                 offs, sorted);
        {
            long long n_threads = (long long)n_right * EMB;
            int blocks = (int)((n_threads + 255) / 256);
            seg_gather_bf16_kernel<<<blocks, 256, 0, stream>>>(
                sorted, offs, (const uint4*)left16, right, c, temp, total,
                out, n_right, n_edges, 1);
        }
        mlp_kernel<<<(n_right + MROWS - 1) / MROWS, 256, 0, stream>>>(
            W1, b1, W2, b2, out, n_right);
    } else {
        // ---------- fallback: atomic path ----------
        float* total = (float*)d_ws;
        hipMemsetAsync(d_out, 0, (size_t)out_size * sizeof(float), stream);
        hipMemsetAsync(d_ws, 0, sizeof(float), stream);
        sum_weights_kernel<<<2048, 256, 0, stream>>>(ew, n_edges, total);
        long long n_threads = (long long)n_edges * EMB;
        long long blocks = (n_threads + 255) / 256;
        edge_scatter_kernel<<<(int)blocks, 256, 0, stream>>>(
            eidx, ew, left, total, out, n_threads);
        int mblocks = (n_right + 255) / 256;
        fused_mlp_kernel<<<mblocks, 256, 0, stream>>>(right, c, temp, W1, b1, W2,
                                                      b2, out, n_right);
    }
}